// Round 1
// baseline (6519.615 us; speedup 1.0000x reference)
//
#include <hip/hip_runtime.h>

#define NN 40000      // nodes
#define NE 400000     // edges (before self loops)
#define NF 16         // in features
#define NH 8          // heads
#define NC 64         // channels per head
#define NR 40         // routes (R1 == R2 == 40)
#define NK 39         // min(R1,R2)-1 logits kept
#define NEG 0.2f      // leaky relu slope

// workspace layout in floats
#define OFF_U    0                            // 2*16*8 = 256  (u_src | u_dst)
#define OFF_AS   256                          // NN*NH
#define OFF_AD   (OFF_AS + NN*NH)             // NN*NH
#define OFF_DEN  (OFF_AD + NN*NH)             // NN*NH
#define OFF_S    (OFF_DEN + NN*NH)            // NN*NH*NF
#define OFF_T    (OFF_S + NN*NH*NF)           // 2*NR*NH*NF
#define OFF_CNT  (OFF_T + 2*NR*NH*NF)         // 2*NR
#define OFF_AGG  (OFF_CNT + 2*NR)             // 2*NR*NH*NC
#define OFF_P    (OFF_AGG + 2*NR*NH*NC)       // 2*NR*NK

// u[f][h] = sum_c W[f, h*64+c] * att[h,c]   (both att_src and att_dst)
__global__ __launch_bounds__(128) void k_u(const float* __restrict__ W,
                                           const float* __restrict__ asrc,
                                           const float* __restrict__ adst,
                                           float* __restrict__ u) {
    int t = threadIdx.x;              // 0..127 = f*8+h
    int f = t >> 3, h = t & 7;
    const float* wrow = W + f * (NH * NC) + h * NC;
    const float* av = asrc + h * NC;
    const float* bv = adst + h * NC;
    float su = 0.f, sv = 0.f;
    for (int c = 0; c < NC; ++c) { su += wrow[c] * av[c]; sv += wrow[c] * bv[c]; }
    u[t] = su;
    u[128 + t] = sv;
}

// a_s[n,h] = x[n,:] . u_src[:,h] ; a_d likewise
__global__ __launch_bounds__(256) void k_a(const float* __restrict__ x,
                                           const float* __restrict__ u,
                                           float* __restrict__ as_,
                                           float* __restrict__ ad_) {
    __shared__ float us[256];
    us[threadIdx.x] = u[threadIdx.x];
    __syncthreads();
    int n = blockIdx.x * 256 + threadIdx.x;
    if (n >= NN) return;
    const float4* xp = (const float4*)(x + n * NF);
    float4 v0 = xp[0], v1 = xp[1], v2 = xp[2], v3 = xp[3];
    float xv[16] = {v0.x, v0.y, v0.z, v0.w, v1.x, v1.y, v1.z, v1.w,
                    v2.x, v2.y, v2.z, v2.w, v3.x, v3.y, v3.z, v3.w};
    for (int h = 0; h < NH; ++h) {
        float s1 = 0.f, s2 = 0.f;
        for (int f = 0; f < NF; ++f) {
            s1 += xv[f] * us[f * 8 + h];
            s2 += xv[f] * us[128 + f * 8 + h];
        }
        as_[n * NH + h] = s1;
        ad_[n * NH + h] = s2;
    }
}

// per (edge, head): w = exp(leakyrelu(a_s[src]+a_d[dst]));
// denom[dst,h] += w ; s[dst,h,f] += w * x[src,f]
__global__ __launch_bounds__(256) void k_edge(const int* __restrict__ ei,
                                              const float* __restrict__ as_,
                                              const float* __restrict__ ad_,
                                              const float* __restrict__ x,
                                              float* __restrict__ den,
                                              float* __restrict__ s) {
    int gid = blockIdx.x * 256 + threadIdx.x;
    if (gid >= (NE + NN) * NH) return;
    int eid = gid >> 3, h = gid & 7;
    int src, dst;
    if (eid < NE) { src = ei[eid]; dst = ei[NE + eid]; }
    else          { src = dst = eid - NE; }      // self loop
    float e = as_[src * NH + h] + ad_[dst * NH + h];
    e = (e > 0.f) ? e : NEG * e;
    float w = __expf(e);
    atomicAdd(den + dst * NH + h, w);
    const float4* xp = (const float4*)(x + src * NF);
    float4 a = xp[0], b = xp[1], c = xp[2], d = xp[3];
    float* sp = s + (dst * NH + h) * NF;
    atomicAdd(sp + 0,  w * a.x); atomicAdd(sp + 1,  w * a.y);
    atomicAdd(sp + 2,  w * a.z); atomicAdd(sp + 3,  w * a.w);
    atomicAdd(sp + 4,  w * b.x); atomicAdd(sp + 5,  w * b.y);
    atomicAdd(sp + 6,  w * b.z); atomicAdd(sp + 7,  w * b.w);
    atomicAdd(sp + 8,  w * c.x); atomicAdd(sp + 9,  w * c.y);
    atomicAdd(sp + 10, w * c.z); atomicAdd(sp + 11, w * c.w);
    atomicAdd(sp + 12, w * d.x); atomicAdd(sp + 13, w * d.y);
    atomicAdd(sp + 14, w * d.z); atomicAdd(sp + 15, w * d.w);
}

// t[route[n], h, f] += s[n,h,f]/denom[n,h] ; cnt[route[n]] += 1
__global__ __launch_bounds__(256) void k_node(const float* __restrict__ s,
                                              const float* __restrict__ den,
                                              const int* __restrict__ route,
                                              float* __restrict__ t,
                                              float* __restrict__ cnt) {
    __shared__ float tl[NR * NH * NF];
    __shared__ float cl[64];
    for (int i = threadIdx.x; i < NR * NH * NF; i += 256) tl[i] = 0.f;
    if (threadIdx.x < 64) cl[threadIdx.x] = 0.f;
    __syncthreads();
    int per = (NN + gridDim.x - 1) / gridDim.x;
    int n0 = blockIdx.x * per;
    int n1 = n0 + per; if (n1 > NN) n1 = NN;
    int ln = threadIdx.x >> 7;        // 0/1 : two nodes per iteration
    int hf = threadIdx.x & 127;
    int hh = hf >> 4;
    for (int n = n0 + ln; n < n1; n += 2) {
        int r = route[n];
        float d = den[n * NH + hh];
        float v = s[n * (NH * NF) + hf] / d;
        atomicAdd(&tl[r * 128 + hf], v);
        if (hf == 0) atomicAdd(&cl[r], 1.0f);
    }
    __syncthreads();
    for (int i = threadIdx.x; i < NR * NH * NF; i += 256) atomicAdd(&t[i], tl[i]);
    if (threadIdx.x < NR) atomicAdd(&cnt[threadIdx.x], cl[threadIdx.x]);
}

// agg[g,i,hc] = sum_f t[g,i,h,f]*W[f,hc] + cnt[g,i]*bias[hc]
__global__ __launch_bounds__(256) void k_agg(const float* __restrict__ t,
                                             const float* __restrict__ cnt,
                                             const float* __restrict__ W,
                                             const float* __restrict__ bias,
                                             float* __restrict__ agg) {
    int gid = blockIdx.x * 256 + threadIdx.x;
    if (gid >= 2 * NR * NH * NC) return;
    int g = gid / (NR * NH * NC);
    int rem = gid - g * (NR * NH * NC);
    int i = rem >> 9;
    int hc = rem & 511;
    int h = hc >> 6;
    const float* tp = t + g * (NR * NH * NF) + i * (NH * NF) + h * NF;
    float acc = cnt[g * NR + i] * bias[hc];
    for (int f = 0; f < NF; ++f) acc += tp[f] * W[f * (NH * NC) + hc];
    agg[gid] = acc;
}

// P[g,i,k] = agg[g,i,:] . W_head[g*512:(g+1)*512, k]   (k < NK)
__global__ __launch_bounds__(256) void k_p(const float* __restrict__ agg,
                                           const float* __restrict__ Wh,
                                           float* __restrict__ P) {
    int gid = blockIdx.x * 256 + threadIdx.x;
    if (gid >= 2 * NR * NK) return;
    int g = gid / (NR * NK);
    int rem = gid - g * (NR * NK);
    int i = rem / NK;
    int k = rem - i * NK;
    const float* ap = agg + (g * NR + i) * 512;
    const float* wp = Wh + (g * 512) * 61 + k;
    float acc = 0.f;
    for (int d = 0; d < 512; ++d) acc += ap[d] * wp[d * 61];
    P[gid] = acc;
}

// logits[i,j,k] = P1[i,k]+P2[j,k]+b[k]; probs = softmax over all 62400
__global__ __launch_bounds__(1024) void k_final(const float* __restrict__ P,
                                                const float* __restrict__ bh,
                                                float* __restrict__ out) {
    __shared__ float p1[NR * NK], p2[NR * NK], bsh[NK];
    __shared__ float red[16];
    __shared__ float bc[2];
    int tid = threadIdx.x;
    for (int i = tid; i < NR * NK; i += 1024) { p1[i] = P[i]; p2[i] = P[NR * NK + i]; }
    if (tid < NK) bsh[tid] = bh[tid];
    __syncthreads();
    const int TOT = NR * NR * NK;
    float m = -3.0e38f;
    for (int idx = tid; idx < TOT; idx += 1024) {
        int i = idx / (NR * NK);
        int r = idx - i * (NR * NK);
        int j = r / NK;
        int k = r - j * NK;
        float l = p1[i * NK + k] + p2[j * NK + k] + bsh[k];
        m = fmaxf(m, l);
    }
    for (int off = 32; off > 0; off >>= 1) m = fmaxf(m, __shfl_down(m, off));
    if ((tid & 63) == 0) red[tid >> 6] = m;
    __syncthreads();
    if (tid == 0) {
        float g = red[0];
        for (int w = 1; w < 16; ++w) g = fmaxf(g, red[w]);
        bc[0] = g;
    }
    __syncthreads();
    float gm = bc[0];
    __syncthreads();
    float sum = 0.f;
    for (int idx = tid; idx < TOT; idx += 1024) {
        int i = idx / (NR * NK);
        int r = idx - i * (NR * NK);
        int j = r / NK;
        int k = r - j * NK;
        float l = p1[i * NK + k] + p2[j * NK + k] + bsh[k];
        sum += __expf(l - gm);
    }
    for (int off = 32; off > 0; off >>= 1) sum += __shfl_down(sum, off);
    if ((tid & 63) == 0) red[tid >> 6] = sum;
    __syncthreads();
    if (tid == 0) {
        float g = 0.f;
        for (int w = 0; w < 16; ++w) g += red[w];
        bc[1] = 1.0f / g;
    }
    __syncthreads();
    float inv = bc[1];
    for (int idx = tid; idx < TOT; idx += 1024) {
        int i = idx / (NR * NK);
        int r = idx - i * (NR * NK);
        int j = r / NK;
        int k = r - j * NK;
        float l = p1[i * NK + k] + p2[j * NK + k] + bsh[k];
        out[idx] = __expf(l - gm) * inv;
    }
}

extern "C" void kernel_launch(void* const* d_in, const int* in_sizes, int n_in,
                              void* d_out, int out_size, void* d_ws, size_t ws_size,
                              hipStream_t stream) {
    const float* x1   = (const float*)d_in[0];
    const int*   ei1  = (const int*)d_in[1];
    const int*   rv1  = (const int*)d_in[3];
    const float* x2   = (const float*)d_in[5];
    const int*   ei2  = (const int*)d_in[6];
    const int*   rv2  = (const int*)d_in[8];
    const float* Wg   = (const float*)d_in[10];
    const float* asrc = (const float*)d_in[11];
    const float* adst = (const float*)d_in[12];
    const float* bias = (const float*)d_in[13];
    const float* Wh   = (const float*)d_in[14];
    const float* bh   = (const float*)d_in[15];
    float* out = (float*)d_out;
    float* ws  = (float*)d_ws;

    float* u   = ws + OFF_U;
    float* as_ = ws + OFF_AS;
    float* ad_ = ws + OFF_AD;
    float* den = ws + OFF_DEN;
    float* s   = ws + OFF_S;
    float* t   = ws + OFF_T;
    float* cnt = ws + OFF_CNT;
    float* agg = ws + OFF_AGG;
    float* P   = ws + OFF_P;

    // zero route-level accumulators (t and cnt are contiguous)
    hipMemsetAsync(t, 0, (size_t)(2 * NR * NH * NF + 2 * NR) * sizeof(float), stream);
    k_u<<<1, 128, 0, stream>>>(Wg, asrc, adst, u);

    const float* xs[2]  = {x1, x2};
    const int*   eis[2] = {ei1, ei2};
    const int*   rvs[2] = {rv1, rv2};
    for (int g = 0; g < 2; ++g) {
        // zero denom + s (contiguous)
        hipMemsetAsync(den, 0, (size_t)(NN * NH + NN * NH * NF) * sizeof(float), stream);
        k_a<<<(NN + 255) / 256, 256, 0, stream>>>(xs[g], u, as_, ad_);
        k_edge<<<((NE + NN) * NH + 255) / 256, 256, 0, stream>>>(eis[g], as_, ad_, xs[g], den, s);
        k_node<<<128, 256, 0, stream>>>(s, den, rvs[g], t + g * NR * NH * NF, cnt + g * NR);
    }
    k_agg<<<(2 * NR * NH * NC + 255) / 256, 256, 0, stream>>>(t, cnt, Wg, bias, agg);
    k_p<<<(2 * NR * NK + 255) / 256, 256, 0, stream>>>(agg, Wh, P);
    k_final<<<1, 1024, 0, stream>>>(P, bh, out);
}

// Round 2
// 625.702 us; speedup vs baseline: 10.4197x; 10.4197x over previous
//
#include <hip/hip_runtime.h>

#define NN 40000      // nodes
#define NE 400000     // edges (before self loops)
#define NF 16         // in features
#define NH 8          // heads
#define NC 64         // channels per head
#define NR 40         // routes (R1 == R2 == 40)
#define NK 39         // min(R1,R2)-1 logits kept
#define NEG 0.2f      // leaky relu slope

// workspace layout (floats)
#define OFF_U    0                            // 256  (u_src | u_dst)
#define OFF_AS   256                          // NN*NH
#define OFF_AD   (OFF_AS + NN*NH)             // NN*NH
#define OFF_S    (OFF_AD + NN*NH)             // NN*NH*NF (normalized)
#define OFF_T    (OFF_S + NN*NH*NF)           // 2*NR*NH*NF
#define OFF_CNT  (OFF_T + 2*NR*NH*NF)         // 2*NR
#define OFF_AGG  (OFF_CNT + 2*NR)             // 2*NR*NH*NC
#define OFF_P    (OFF_AGG + 2*NR*NH*NC)       // 2*NR*NK
#define OFF_INT  (OFF_P + 2*NR*NK)            // int region starts here (float slots)
// int region layout (in ints, relative to OFF_INT)
#define IOFF_DEG   0            // NN
#define IOFF_ROW   NN           // NN+1
#define IOFF_CUR   (2*NN + 1)   // NN
#define IOFF_SRC   (3*NN + 1)   // NE

// u[f][h] = sum_c W[f, h*64+c] * att[h,c]   (both att_src and att_dst)
__global__ __launch_bounds__(128) void k_u(const float* __restrict__ W,
                                           const float* __restrict__ asrc,
                                           const float* __restrict__ adst,
                                           float* __restrict__ u) {
    int t = threadIdx.x;              // 0..127 = f*8+h
    int f = t >> 3, h = t & 7;
    const float* wrow = W + f * (NH * NC) + h * NC;
    const float* av = asrc + h * NC;
    const float* bv = adst + h * NC;
    float su = 0.f, sv = 0.f;
    for (int c = 0; c < NC; ++c) { su += wrow[c] * av[c]; sv += wrow[c] * bv[c]; }
    u[t] = su;
    u[128 + t] = sv;
}

// a_s[n,h] = x[n,:] . u_src[:,h] ; a_d likewise
__global__ __launch_bounds__(256) void k_a(const float* __restrict__ x,
                                           const float* __restrict__ u,
                                           float* __restrict__ as_,
                                           float* __restrict__ ad_) {
    __shared__ float us[256];
    us[threadIdx.x] = u[threadIdx.x];
    __syncthreads();
    int n = blockIdx.x * 256 + threadIdx.x;
    if (n >= NN) return;
    const float4* xp = (const float4*)(x + n * NF);
    float4 v0 = xp[0], v1 = xp[1], v2 = xp[2], v3 = xp[3];
    float xv[16] = {v0.x, v0.y, v0.z, v0.w, v1.x, v1.y, v1.z, v1.w,
                    v2.x, v2.y, v2.z, v2.w, v3.x, v3.y, v3.z, v3.w};
    for (int h = 0; h < NH; ++h) {
        float s1 = 0.f, s2 = 0.f;
        for (int f = 0; f < NF; ++f) {
            s1 += xv[f] * us[f * 8 + h];
            s2 += xv[f] * us[128 + f * 8 + h];
        }
        as_[n * NH + h] = s1;
        ad_[n * NH + h] = s2;
    }
}

// deg[dst] histogram over real edges
__global__ __launch_bounds__(256) void k_hist(const int* __restrict__ ei,
                                              int* __restrict__ deg) {
    int gid = blockIdx.x * 256 + threadIdx.x;
    if (gid >= NE) return;
    atomicAdd(&deg[ei[NE + gid]], 1);
}

// single-block exclusive scan of deg[NN] -> rowptr[NN+1], cursor[NN]
__global__ __launch_bounds__(1024) void k_scan(const int* __restrict__ deg,
                                               int* __restrict__ rowptr,
                                               int* __restrict__ cursor) {
    __shared__ int ls[1024];
    int t = threadIdx.x;
    const int CH = (NN + 1023) / 1024;    // 40
    int i0 = t * CH;
    int lsum = 0;
    for (int i = 0; i < CH; ++i) {
        int idx = i0 + i;
        if (idx < NN) lsum += deg[idx];
    }
    ls[t] = lsum;
    __syncthreads();
    for (int off = 1; off < 1024; off <<= 1) {
        int v = (t >= off) ? ls[t - off] : 0;
        __syncthreads();
        ls[t] += v;
        __syncthreads();
    }
    int run = (t == 0) ? 0 : ls[t - 1];
    for (int i = 0; i < CH; ++i) {
        int idx = i0 + i;
        if (idx < NN) {
            rowptr[idx] = run;
            cursor[idx] = run;
            run += deg[idx];
        }
    }
    if (t == 1023) rowptr[NN] = ls[1023];
}

// scatter src ids into CSR order
__global__ __launch_bounds__(256) void k_scatter(const int* __restrict__ ei,
                                                 int* __restrict__ cursor,
                                                 int* __restrict__ srcs) {
    int gid = blockIdx.x * 256 + threadIdx.x;
    if (gid >= NE) return;
    int dstv = ei[NE + gid];
    int pos = atomicAdd(&cursor[dstv], 1);
    srcs[pos] = ei[gid];
}

// per dst: s[dst,h,f] = (w_self*x[dst,f] + sum_e w_e*x[src_e,f]) / (w_self + sum w_e)
// 128 threads per dst (t = h*16+f), 2 dst per block. No atomics.
__global__ __launch_bounds__(256) void k_gather(const int* __restrict__ rowptr,
                                                const int* __restrict__ srcs,
                                                const float* __restrict__ as_,
                                                const float* __restrict__ ad_,
                                                const float* __restrict__ x,
                                                float* __restrict__ s) {
    int d = blockIdx.x * 2 + (threadIdx.x >> 7);
    if (d >= NN) return;
    int t = threadIdx.x & 127;
    int h = t >> 4, f = t & 15;
    float adv = ad_[d * NH + h];
    // self loop
    float e0 = as_[d * NH + h] + adv;
    e0 = (e0 > 0.f) ? e0 : NEG * e0;
    float w0 = __expf(e0);
    float wsum = w0;
    float acc = w0 * x[d * NF + f];
    int eend = rowptr[d + 1];
    for (int e = rowptr[d]; e < eend; ++e) {
        int src = srcs[e];
        float ev = as_[src * NH + h] + adv;
        ev = (ev > 0.f) ? ev : NEG * ev;
        float w = __expf(ev);
        wsum += w;
        acc += w * x[src * NF + f];
    }
    s[d * 128 + t] = acc / wsum;
}

// t[route[n], h, f] += s[n,h,f] ; cnt[route[n]] += 1   (s already normalized)
__global__ __launch_bounds__(256) void k_node(const float* __restrict__ s,
                                              const int* __restrict__ route,
                                              float* __restrict__ t,
                                              float* __restrict__ cnt) {
    __shared__ float tl[NR * NH * NF];
    __shared__ float cl[64];
    for (int i = threadIdx.x; i < NR * NH * NF; i += 256) tl[i] = 0.f;
    if (threadIdx.x < 64) cl[threadIdx.x] = 0.f;
    __syncthreads();
    int per = (NN + gridDim.x - 1) / gridDim.x;
    int n0 = blockIdx.x * per;
    int n1 = n0 + per; if (n1 > NN) n1 = NN;
    int ln = threadIdx.x >> 7;
    int hf = threadIdx.x & 127;
    for (int n = n0 + ln; n < n1; n += 2) {
        int r = route[n];
        float v = s[n * 128 + hf];
        atomicAdd(&tl[r * 128 + hf], v);
        if (hf == 0) atomicAdd(&cl[r], 1.0f);
    }
    __syncthreads();
    for (int i = threadIdx.x; i < NR * NH * NF; i += 256) atomicAdd(&t[i], tl[i]);
    if (threadIdx.x < NR) atomicAdd(&cnt[threadIdx.x], cl[threadIdx.x]);
}

// agg[g,i,hc] = sum_f t[g,i,h,f]*W[f,hc] + cnt[g,i]*bias[hc]
__global__ __launch_bounds__(256) void k_agg(const float* __restrict__ t,
                                             const float* __restrict__ cnt,
                                             const float* __restrict__ W,
                                             const float* __restrict__ bias,
                                             float* __restrict__ agg) {
    int gid = blockIdx.x * 256 + threadIdx.x;
    if (gid >= 2 * NR * NH * NC) return;
    int g = gid / (NR * NH * NC);
    int rem = gid - g * (NR * NH * NC);
    int i = rem >> 9;
    int hc = rem & 511;
    int h = hc >> 6;
    const float* tp = t + g * (NR * NH * NF) + i * (NH * NF) + h * NF;
    float acc = cnt[g * NR + i] * bias[hc];
    for (int f = 0; f < NF; ++f) acc += tp[f] * W[f * (NH * NC) + hc];
    agg[gid] = acc;
}

// P[g,i,k] = agg[g,i,:] . W_head[g*512:(g+1)*512, k]   (k < NK)
__global__ __launch_bounds__(256) void k_p(const float* __restrict__ agg,
                                           const float* __restrict__ Wh,
                                           float* __restrict__ P) {
    int gid = blockIdx.x * 256 + threadIdx.x;
    if (gid >= 2 * NR * NK) return;
    int g = gid / (NR * NK);
    int rem = gid - g * (NR * NK);
    int i = rem / NK;
    int k = rem - i * NK;
    const float* ap = agg + (g * NR + i) * 512;
    const float* wp = Wh + (g * 512) * 61 + k;
    float acc = 0.f;
    for (int d = 0; d < 512; ++d) acc += ap[d] * wp[d * 61];
    P[gid] = acc;
}

// logits[i,j,k] = P1[i,k]+P2[j,k]+b[k]; probs = softmax over all 62400
__global__ __launch_bounds__(1024) void k_final(const float* __restrict__ P,
                                                const float* __restrict__ bh,
                                                float* __restrict__ out) {
    __shared__ float p1[NR * NK], p2[NR * NK], bsh[NK];
    __shared__ float red[16];
    __shared__ float bc[2];
    int tid = threadIdx.x;
    for (int i = tid; i < NR * NK; i += 1024) { p1[i] = P[i]; p2[i] = P[NR * NK + i]; }
    if (tid < NK) bsh[tid] = bh[tid];
    __syncthreads();
    const int TOT = NR * NR * NK;
    float m = -3.0e38f;
    for (int idx = tid; idx < TOT; idx += 1024) {
        int i = idx / (NR * NK);
        int r = idx - i * (NR * NK);
        int j = r / NK;
        int k = r - j * NK;
        float l = p1[i * NK + k] + p2[j * NK + k] + bsh[k];
        m = fmaxf(m, l);
    }
    for (int off = 32; off > 0; off >>= 1) m = fmaxf(m, __shfl_down(m, off));
    if ((tid & 63) == 0) red[tid >> 6] = m;
    __syncthreads();
    if (tid == 0) {
        float g = red[0];
        for (int w = 1; w < 16; ++w) g = fmaxf(g, red[w]);
        bc[0] = g;
    }
    __syncthreads();
    float gm = bc[0];
    __syncthreads();
    float sum = 0.f;
    for (int idx = tid; idx < TOT; idx += 1024) {
        int i = idx / (NR * NK);
        int r = idx - i * (NR * NK);
        int j = r / NK;
        int k = r - j * NK;
        float l = p1[i * NK + k] + p2[j * NK + k] + bsh[k];
        sum += __expf(l - gm);
    }
    for (int off = 32; off > 0; off >>= 1) sum += __shfl_down(sum, off);
    if ((tid & 63) == 0) red[tid >> 6] = sum;
    __syncthreads();
    if (tid == 0) {
        float g = 0.f;
        for (int w = 0; w < 16; ++w) g += red[w];
        bc[1] = 1.0f / g;
    }
    __syncthreads();
    float inv = bc[1];
    for (int idx = tid; idx < TOT; idx += 1024) {
        int i = idx / (NR * NK);
        int r = idx - i * (NR * NK);
        int j = r / NK;
        int k = r - j * NK;
        float l = p1[i * NK + k] + p2[j * NK + k] + bsh[k];
        out[idx] = __expf(l - gm) * inv;
    }
}

extern "C" void kernel_launch(void* const* d_in, const int* in_sizes, int n_in,
                              void* d_out, int out_size, void* d_ws, size_t ws_size,
                              hipStream_t stream) {
    const float* x1   = (const float*)d_in[0];
    const int*   ei1  = (const int*)d_in[1];
    const int*   rv1  = (const int*)d_in[3];
    const float* x2   = (const float*)d_in[5];
    const int*   ei2  = (const int*)d_in[6];
    const int*   rv2  = (const int*)d_in[8];
    const float* Wg   = (const float*)d_in[10];
    const float* asrc = (const float*)d_in[11];
    const float* adst = (const float*)d_in[12];
    const float* bias = (const float*)d_in[13];
    const float* Wh   = (const float*)d_in[14];
    const float* bh   = (const float*)d_in[15];
    float* out = (float*)d_out;
    float* ws  = (float*)d_ws;

    float* u   = ws + OFF_U;
    float* as_ = ws + OFF_AS;
    float* ad_ = ws + OFF_AD;
    float* s   = ws + OFF_S;
    float* t   = ws + OFF_T;
    float* cnt = ws + OFF_CNT;
    float* agg = ws + OFF_AGG;
    float* P   = ws + OFF_P;
    int*   ibase  = (int*)(ws + OFF_INT);
    int*   deg    = ibase + IOFF_DEG;
    int*   rowptr = ibase + IOFF_ROW;
    int*   cursor = ibase + IOFF_CUR;
    int*   srcs   = ibase + IOFF_SRC;

    // zero route-level accumulators (t and cnt are contiguous)
    hipMemsetAsync(t, 0, (size_t)(2 * NR * NH * NF + 2 * NR) * sizeof(float), stream);
    k_u<<<1, 128, 0, stream>>>(Wg, asrc, adst, u);

    const float* xs[2]  = {x1, x2};
    const int*   eis[2] = {ei1, ei2};
    const int*   rvs[2] = {rv1, rv2};
    for (int g = 0; g < 2; ++g) {
        hipMemsetAsync(deg, 0, (size_t)NN * sizeof(int), stream);
        k_a<<<(NN + 255) / 256, 256, 0, stream>>>(xs[g], u, as_, ad_);
        k_hist<<<(NE + 255) / 256, 256, 0, stream>>>(eis[g], deg);
        k_scan<<<1, 1024, 0, stream>>>(deg, rowptr, cursor);
        k_scatter<<<(NE + 255) / 256, 256, 0, stream>>>(eis[g], cursor, srcs);
        k_gather<<<(NN + 1) / 2, 256, 0, stream>>>(rowptr, srcs, as_, ad_, xs[g], s);
        k_node<<<128, 256, 0, stream>>>(s, rvs[g], t + g * NR * NH * NF, cnt + g * NR);
    }
    k_agg<<<(2 * NR * NH * NC + 255) / 256, 256, 0, stream>>>(t, cnt, Wg, bias, agg);
    k_p<<<(2 * NR * NK + 255) / 256, 256, 0, stream>>>(agg, Wh, P);
    k_final<<<1, 1024, 0, stream>>>(P, bh, out);
}

// Round 3
// 458.718 us; speedup vs baseline: 14.2127x; 1.3640x over previous
//
#include <hip/hip_runtime.h>

#define NN 40000      // nodes
#define NE 400000     // edges (before self loops)
#define NF 16         // in features
#define NH 8          // heads
#define NC 64         // channels per head
#define NR 40         // routes (R1 == R2 == 40)
#define NK 39         // min(R1,R2)-1 logits kept
#define NEG 0.2f      // leaky relu slope

// workspace layout (floats)
#define OFF_U    0                            // 256  (u_src | u_dst)
#define OFF_AS   256                          // NN*NH
#define OFF_AD   (OFF_AS + NN*NH)             // NN*NH
#define OFF_S    (OFF_AD + NN*NH)             // NN*NH*NF (normalized)
#define OFF_T    (OFF_S + NN*NH*NF)           // 2*NR*NH*NF
#define OFF_CNT  (OFF_T + 2*NR*NH*NF)         // 2*NR
#define OFF_AGG  (OFF_CNT + 2*NR)             // 2*NR*NH*NC
#define OFF_P    (OFF_AGG + 2*NR*NH*NC)       // 2*NR*NK
#define OFF_INT  (OFF_P + 2*NR*NK)            // int region starts here
// int region layout (ints, relative to OFF_INT)
#define IOFF_GCNT  0             // 1
#define IOFF_DEG   1             // NN
#define IOFF_START (1 + NN)      // NN
#define IOFF_CUR   (1 + 2*NN)    // NN
#define IOFF_SRC   (1 + 3*NN)    // NE

// u[f][h] = sum_c W[f, h*64+c] * att[h,c]   (both att_src and att_dst)
__global__ __launch_bounds__(128) void k_u(const float* __restrict__ W,
                                           const float* __restrict__ asrc,
                                           const float* __restrict__ adst,
                                           float* __restrict__ u) {
    int t = threadIdx.x;              // 0..127 = f*8+h
    int f = t >> 3, h = t & 7;
    const float* wrow = W + f * (NH * NC) + h * NC;
    const float* av = asrc + h * NC;
    const float* bv = adst + h * NC;
    float su = 0.f, sv = 0.f;
    for (int c = 0; c < NC; ++c) { su += wrow[c] * av[c]; sv += wrow[c] * bv[c]; }
    u[t] = su;
    u[128 + t] = sv;
}

// a_s[n,h] = x[n,:] . u_src[:,h] ; a_d likewise
__global__ __launch_bounds__(256) void k_a(const float* __restrict__ x,
                                           const float* __restrict__ u,
                                           float* __restrict__ as_,
                                           float* __restrict__ ad_) {
    __shared__ float us[256];
    us[threadIdx.x] = u[threadIdx.x];
    __syncthreads();
    int n = blockIdx.x * 256 + threadIdx.x;
    if (n >= NN) return;
    const float4* xp = (const float4*)(x + n * NF);
    float4 v0 = xp[0], v1 = xp[1], v2 = xp[2], v3 = xp[3];
    float xv[16] = {v0.x, v0.y, v0.z, v0.w, v1.x, v1.y, v1.z, v1.w,
                    v2.x, v2.y, v2.z, v2.w, v3.x, v3.y, v3.z, v3.w};
    for (int h = 0; h < NH; ++h) {
        float s1 = 0.f, s2 = 0.f;
        for (int f = 0; f < NF; ++f) {
            s1 += xv[f] * us[f * 8 + h];
            s2 += xv[f] * us[128 + f * 8 + h];
        }
        as_[n * NH + h] = s1;
        ad_[n * NH + h] = s2;
    }
}

// deg[dst] histogram over real edges
__global__ __launch_bounds__(256) void k_hist(const int* __restrict__ ei,
                                              int* __restrict__ deg) {
    int gid = blockIdx.x * 256 + threadIdx.x;
    if (gid >= NE) return;
    atomicAdd(&deg[ei[NE + gid]], 1);
}

// bump-allocate a contiguous segment per node (order-free CSR).
// wave-level prefix scan -> 1 global atomic per wave (625 total).
__global__ __launch_bounds__(256) void k_alloc(const int* __restrict__ deg,
                                               int* __restrict__ start,
                                               int* __restrict__ cur,
                                               int* __restrict__ gcnt) {
    int gid = blockIdx.x * 256 + threadIdx.x;
    int d = (gid < NN) ? deg[gid] : 0;
    int lane = threadIdx.x & 63;
    int p = d;                                   // inclusive wave scan
    for (int off = 1; off < 64; off <<= 1) {
        int v = __shfl_up(p, off);
        if (lane >= off) p += v;
    }
    int wavesum = __shfl(p, 63);
    int base = 0;
    if (lane == 63) base = atomicAdd(gcnt, wavesum);
    base = __shfl(base, 63);
    int s = base + p - d;                        // exclusive position
    if (gid < NN) { start[gid] = s; cur[gid] = s; }
}

// scatter src ids into segment order
__global__ __launch_bounds__(256) void k_scatter(const int* __restrict__ ei,
                                                 int* __restrict__ cursor,
                                                 int* __restrict__ srcs) {
    int gid = blockIdx.x * 256 + threadIdx.x;
    if (gid >= NE) return;
    int dstv = ei[NE + gid];
    int pos = atomicAdd(&cursor[dstv], 1);
    srcs[pos] = ei[gid];
}

// per dst: s[dst,h,f] = (w_self*x[dst,f] + sum_e w_e*x[src_e,f]) / (w_self + sum w_e)
// 128 threads per dst (t = h*16+f), 2 dst per block. No atomics.
__global__ __launch_bounds__(256) void k_gather(const int* __restrict__ start,
                                                const int* __restrict__ deg,
                                                const int* __restrict__ srcs,
                                                const float* __restrict__ as_,
                                                const float* __restrict__ ad_,
                                                const float* __restrict__ x,
                                                float* __restrict__ s) {
    int d = blockIdx.x * 2 + (threadIdx.x >> 7);
    if (d >= NN) return;
    int t = threadIdx.x & 127;
    int h = t >> 4, f = t & 15;
    float adv = ad_[d * NH + h];
    // self loop
    float e0 = as_[d * NH + h] + adv;
    e0 = (e0 > 0.f) ? e0 : NEG * e0;
    float w0 = __expf(e0);
    float wsum = w0;
    float acc = w0 * x[d * NF + f];
    int e = start[d];
    int eend = e + deg[d];
    for (; e < eend; ++e) {
        int src = srcs[e];
        float ev = as_[src * NH + h] + adv;
        ev = (ev > 0.f) ? ev : NEG * ev;
        float w = __expf(ev);
        wsum += w;
        acc += w * x[src * NF + f];
    }
    s[d * 128 + t] = acc / wsum;
}

// t[route[n], h, f] += s[n,h,f] ; cnt[route[n]] += 1   (s already normalized)
__global__ __launch_bounds__(256) void k_node(const float* __restrict__ s,
                                              const int* __restrict__ route,
                                              float* __restrict__ t,
                                              float* __restrict__ cnt) {
    __shared__ float tl[NR * NH * NF];
    __shared__ float cl[64];
    for (int i = threadIdx.x; i < NR * NH * NF; i += 256) tl[i] = 0.f;
    if (threadIdx.x < 64) cl[threadIdx.x] = 0.f;
    __syncthreads();
    int per = (NN + gridDim.x - 1) / gridDim.x;
    int n0 = blockIdx.x * per;
    int n1 = n0 + per; if (n1 > NN) n1 = NN;
    int ln = threadIdx.x >> 7;
    int hf = threadIdx.x & 127;
    for (int n = n0 + ln; n < n1; n += 2) {
        int r = route[n];
        float v = s[n * 128 + hf];
        atomicAdd(&tl[r * 128 + hf], v);
        if (hf == 0) atomicAdd(&cl[r], 1.0f);
    }
    __syncthreads();
    for (int i = threadIdx.x; i < NR * NH * NF; i += 256) atomicAdd(&t[i], tl[i]);
    if (threadIdx.x < NR) atomicAdd(&cnt[threadIdx.x], cl[threadIdx.x]);
}

// agg[g,i,hc] = sum_f t[g,i,h,f]*W[f,hc] + cnt[g,i]*bias[hc]
__global__ __launch_bounds__(256) void k_agg(const float* __restrict__ t,
                                             const float* __restrict__ cnt,
                                             const float* __restrict__ W,
                                             const float* __restrict__ bias,
                                             float* __restrict__ agg) {
    int gid = blockIdx.x * 256 + threadIdx.x;
    if (gid >= 2 * NR * NH * NC) return;
    int g = gid / (NR * NH * NC);
    int rem = gid - g * (NR * NH * NC);
    int i = rem >> 9;
    int hc = rem & 511;
    int h = hc >> 6;
    const float* tp = t + g * (NR * NH * NF) + i * (NH * NF) + h * NF;
    float acc = cnt[g * NR + i] * bias[hc];
    for (int f = 0; f < NF; ++f) acc += tp[f] * W[f * (NH * NC) + hc];
    agg[gid] = acc;
}

// P[g,i,k] = agg[g,i,:] . W_head[g*512:(g+1)*512, k]   (k < NK)
__global__ __launch_bounds__(256) void k_p(const float* __restrict__ agg,
                                           const float* __restrict__ Wh,
                                           float* __restrict__ P) {
    int gid = blockIdx.x * 256 + threadIdx.x;
    if (gid >= 2 * NR * NK) return;
    int g = gid / (NR * NK);
    int rem = gid - g * (NR * NK);
    int i = rem / NK;
    int k = rem - i * NK;
    const float* ap = agg + (g * NR + i) * 512;
    const float* wp = Wh + (g * 512) * 61 + k;
    float acc = 0.f;
    for (int d = 0; d < 512; ++d) acc += ap[d] * wp[d * 61];
    P[gid] = acc;
}

// logits[i,j,k] = P1[i,k]+P2[j,k]+b[k]; probs = softmax over all 62400
__global__ __launch_bounds__(1024) void k_final(const float* __restrict__ P,
                                                const float* __restrict__ bh,
                                                float* __restrict__ out) {
    __shared__ float p1[NR * NK], p2[NR * NK], bsh[NK];
    __shared__ float red[16];
    __shared__ float bc[2];
    int tid = threadIdx.x;
    for (int i = tid; i < NR * NK; i += 1024) { p1[i] = P[i]; p2[i] = P[NR * NK + i]; }
    if (tid < NK) bsh[tid] = bh[tid];
    __syncthreads();
    const int TOT = NR * NR * NK;
    float m = -3.0e38f;
    for (int idx = tid; idx < TOT; idx += 1024) {
        int i = idx / (NR * NK);
        int r = idx - i * (NR * NK);
        int j = r / NK;
        int k = r - j * NK;
        float l = p1[i * NK + k] + p2[j * NK + k] + bsh[k];
        m = fmaxf(m, l);
    }
    for (int off = 32; off > 0; off >>= 1) m = fmaxf(m, __shfl_down(m, off));
    if ((tid & 63) == 0) red[tid >> 6] = m;
    __syncthreads();
    if (tid == 0) {
        float g = red[0];
        for (int w = 1; w < 16; ++w) g = fmaxf(g, red[w]);
        bc[0] = g;
    }
    __syncthreads();
    float gm = bc[0];
    __syncthreads();
    float sum = 0.f;
    for (int idx = tid; idx < TOT; idx += 1024) {
        int i = idx / (NR * NK);
        int r = idx - i * (NR * NK);
        int j = r / NK;
        int k = r - j * NK;
        float l = p1[i * NK + k] + p2[j * NK + k] + bsh[k];
        sum += __expf(l - gm);
    }
    for (int off = 32; off > 0; off >>= 1) sum += __shfl_down(sum, off);
    if ((tid & 63) == 0) red[tid >> 6] = sum;
    __syncthreads();
    if (tid == 0) {
        float g = 0.f;
        for (int w = 0; w < 16; ++w) g += red[w];
        bc[1] = 1.0f / g;
    }
    __syncthreads();
    float inv = bc[1];
    for (int idx = tid; idx < TOT; idx += 1024) {
        int i = idx / (NR * NK);
        int r = idx - i * (NR * NK);
        int j = r / NK;
        int k = r - j * NK;
        float l = p1[i * NK + k] + p2[j * NK + k] + bsh[k];
        out[idx] = __expf(l - gm) * inv;
    }
}

extern "C" void kernel_launch(void* const* d_in, const int* in_sizes, int n_in,
                              void* d_out, int out_size, void* d_ws, size_t ws_size,
                              hipStream_t stream) {
    const float* x1   = (const float*)d_in[0];
    const int*   ei1  = (const int*)d_in[1];
    const int*   rv1  = (const int*)d_in[3];
    const float* x2   = (const float*)d_in[5];
    const int*   ei2  = (const int*)d_in[6];
    const int*   rv2  = (const int*)d_in[8];
    const float* Wg   = (const float*)d_in[10];
    const float* asrc = (const float*)d_in[11];
    const float* adst = (const float*)d_in[12];
    const float* bias = (const float*)d_in[13];
    const float* Wh   = (const float*)d_in[14];
    const float* bh   = (const float*)d_in[15];
    float* out = (float*)d_out;
    float* ws  = (float*)d_ws;

    float* u   = ws + OFF_U;
    float* as_ = ws + OFF_AS;
    float* ad_ = ws + OFF_AD;
    float* s   = ws + OFF_S;
    float* t   = ws + OFF_T;
    float* cnt = ws + OFF_CNT;
    float* agg = ws + OFF_AGG;
    float* P   = ws + OFF_P;
    int*   ibase  = (int*)(ws + OFF_INT);
    int*   gcnt   = ibase + IOFF_GCNT;
    int*   deg    = ibase + IOFF_DEG;
    int*   start  = ibase + IOFF_START;
    int*   cursor = ibase + IOFF_CUR;
    int*   srcs   = ibase + IOFF_SRC;

    // zero route-level accumulators (t and cnt are contiguous)
    hipMemsetAsync(t, 0, (size_t)(2 * NR * NH * NF + 2 * NR) * sizeof(float), stream);
    k_u<<<1, 128, 0, stream>>>(Wg, asrc, adst, u);

    const float* xs[2]  = {x1, x2};
    const int*   eis[2] = {ei1, ei2};
    const int*   rvs[2] = {rv1, rv2};
    for (int g = 0; g < 2; ++g) {
        hipMemsetAsync(gcnt, 0, (size_t)(NN + 1) * sizeof(int), stream);  // gcnt + deg
        k_a<<<(NN + 255) / 256, 256, 0, stream>>>(xs[g], u, as_, ad_);
        k_hist<<<(NE + 255) / 256, 256, 0, stream>>>(eis[g], deg);
        k_alloc<<<(NN + 255) / 256, 256, 0, stream>>>(deg, start, cursor, gcnt);
        k_scatter<<<(NE + 255) / 256, 256, 0, stream>>>(eis[g], cursor, srcs);
        k_gather<<<(NN + 1) / 2, 256, 0, stream>>>(start, deg, srcs, as_, ad_, xs[g], s);
        k_node<<<128, 256, 0, stream>>>(s, rvs[g], t + g * NR * NH * NF, cnt + g * NR);
    }
    k_agg<<<(2 * NR * NH * NC + 255) / 256, 256, 0, stream>>>(t, cnt, Wg, bias, agg);
    k_p<<<(2 * NR * NK + 255) / 256, 256, 0, stream>>>(agg, Wh, P);
    k_final<<<1, 1024, 0, stream>>>(P, bh, out);
}

// Round 4
// 424.594 us; speedup vs baseline: 15.3549x; 1.0804x over previous
//
#include <hip/hip_runtime.h>

#define NN 40000      // nodes
#define NE 400000     // edges (before self loops)
#define NF 16         // in features
#define NH 8          // heads
#define NR 40         // routes
#define NK 39         // min(R1,R2)-1 logits kept
#define NEG 0.2f      // leaky relu slope
#define NBLK 157      // (NN+255)/256
#define PARTN 64      // partial tiles per graph
#define TSZ (NR*128)  // 5120
#define PSZ (TSZ+40)  // 5160 (t tile + cnt)

// float region offsets
#define OFF_AS   0                        // [2][NN*NH]
#define OFF_AD   (OFF_AS + 2*NN*NH)       // [2][NN*NH]
#define OFF_T    (OFF_AD + 2*NN*NH)       // [2][TSZ]
#define OFF_CNT  (OFF_T + 2*TSZ)          // [2][NR]
#define OFF_P    (OFF_CNT + 2*NR)         // [2][NR*NK]
#define OFF_PART (OFF_P + 2*NR*NK)        // [2][PARTN][PSZ]
#define OFF_S    (OFF_PART + 2*PARTN*PSZ) // NN*64 uints (2 bf16 each)
#define OFF_INT  (OFF_S + NN*64)
// int region (relative)
#define IOFF_GCNT  0             // 2
#define IOFF_DEG   2             // 2*NN
#define IOFF_START (2 + 2*NN)    // 2*NN
#define IOFF_CUR   (2 + 4*NN)    // 2*NN
#define IOFF_SRC   (2 + 6*NN)    // 2*NE

static __device__ __forceinline__ unsigned int f2bf(float v) {
    unsigned int x = __float_as_uint(v);
    return (x + 0x7FFFu + ((x >> 16) & 1u)) >> 16;   // round-nearest-even
}
static __device__ __forceinline__ float bf2f(unsigned int u) {
    return __uint_as_float(u << 16);
}

// batched over both graphs: u computed inline per block, then a_s/a_d per node
__global__ __launch_bounds__(256) void k_a(const float* __restrict__ x1,
                                           const float* __restrict__ x2,
                                           const float* __restrict__ W,
                                           const float* __restrict__ asrc,
                                           const float* __restrict__ adst,
                                           float* __restrict__ as_,
                                           float* __restrict__ ad_) {
    __shared__ float us[256];
    int tid = threadIdx.x;
    {
        int tt = tid & 127;
        int f = tt >> 3, h = tt & 7;
        const float* av = (tid < 128 ? asrc : adst) + h * 64;
        const float* wrow = W + f * 512 + h * 64;
        float su = 0.f;
        for (int c = 0; c < 64; ++c) su += wrow[c] * av[c];
        us[tid] = su;      // [0:128) = u_src(f,h), [128:256) = u_dst(f,h)
    }
    __syncthreads();
    int g = blockIdx.x / NBLK;
    int n = (blockIdx.x - g * NBLK) * 256 + tid;
    if (n >= NN) return;
    const float* x = g ? x2 : x1;
    const float4* xp = (const float4*)(x + n * NF);
    float4 v0 = xp[0], v1 = xp[1], v2 = xp[2], v3 = xp[3];
    float xv[16] = {v0.x, v0.y, v0.z, v0.w, v1.x, v1.y, v1.z, v1.w,
                    v2.x, v2.y, v2.z, v2.w, v3.x, v3.y, v3.z, v3.w};
    int o = g * NN * NH + n * NH;
    for (int h = 0; h < NH; ++h) {
        float s1 = 0.f, s2 = 0.f;
        for (int f = 0; f < NF; ++f) {
            s1 += xv[f] * us[f * 8 + h];
            s2 += xv[f] * us[128 + f * 8 + h];
        }
        as_[o + h] = s1;
        ad_[o + h] = s2;
    }
}

// dst-degree histogram, both graphs
__global__ __launch_bounds__(256) void k_hist(const int* __restrict__ ei1,
                                              const int* __restrict__ ei2,
                                              int* __restrict__ deg) {
    int gid = blockIdx.x * 256 + threadIdx.x;
    if (gid >= 2 * NE) return;
    int g = gid >= NE;
    int e = gid - g * NE;
    const int* ei = g ? ei2 : ei1;
    atomicAdd(&deg[g * NN + ei[NE + e]], 1);
}

// bump-allocate contiguous segment per node; 1 global atomic per wave
__global__ __launch_bounds__(256) void k_alloc(const int* __restrict__ deg,
                                               int* __restrict__ start,
                                               int* __restrict__ cur,
                                               int* __restrict__ gcnt) {
    int g = blockIdx.x / NBLK;
    int n = (blockIdx.x - g * NBLK) * 256 + threadIdx.x;
    int d = (n < NN) ? deg[g * NN + n] : 0;
    int lane = threadIdx.x & 63;
    int p = d;
    for (int off = 1; off < 64; off <<= 1) {
        int v = __shfl_up(p, off);
        if (lane >= off) p += v;
    }
    int wavesum = __shfl(p, 63);
    int base = 0;
    if (lane == 63) base = atomicAdd(&gcnt[g], wavesum);
    base = __shfl(base, 63);
    int s = base + p - d;
    if (n < NN) { start[g * NN + n] = s; cur[g * NN + n] = s; }
}

// scatter src ids into segment order, both graphs
__global__ __launch_bounds__(256) void k_scatter(const int* __restrict__ ei1,
                                                 const int* __restrict__ ei2,
                                                 int* __restrict__ cur,
                                                 int* __restrict__ srcs) {
    int gid = blockIdx.x * 256 + threadIdx.x;
    if (gid >= 2 * NE) return;
    int g = gid >= NE;
    int e = gid - g * NE;
    const int* ei = g ? ei2 : ei1;
    int dstv = ei[NE + e];
    int pos = atomicAdd(&cur[g * NN + dstv], 1);
    srcs[g * NE + pos] = ei[e];
}

// per dst (64 lanes: h = lane>>3, fp = lane&7 -> float2), edges unrolled x2,
// output packed bf16 pair per lane. Pointers pre-offset per graph.
__global__ __launch_bounds__(256) void k_gather(const int* __restrict__ start,
                                                const int* __restrict__ deg,
                                                const int* __restrict__ srcs,
                                                const float* __restrict__ as_,
                                                const float* __restrict__ ad_,
                                                const float* __restrict__ x,
                                                unsigned int* __restrict__ sb) {
    int d = blockIdx.x * 4 + (threadIdx.x >> 6);
    int lane = threadIdx.x & 63;
    int h = lane >> 3, fp = lane & 7;
    float adv = ad_[d * NH + h];
    float e0 = as_[d * NH + h] + adv;
    e0 = (e0 > 0.f) ? e0 : NEG * e0;
    float w0 = __expf(e0);
    float2 xv = *(const float2*)(x + d * NF + fp * 2);
    float wsum = w0;
    float ax = w0 * xv.x, ay = w0 * xv.y;
    int base = start[d], dg = deg[d];
    int e = 0;
    for (; e + 1 < dg; e += 2) {
        int s0 = srcs[base + e], s1 = srcs[base + e + 1];
        float ev0 = as_[s0 * NH + h] + adv;
        float ev1 = as_[s1 * NH + h] + adv;
        float2 xa = *(const float2*)(x + s0 * NF + fp * 2);
        float2 xb = *(const float2*)(x + s1 * NF + fp * 2);
        ev0 = (ev0 > 0.f) ? ev0 : NEG * ev0;
        ev1 = (ev1 > 0.f) ? ev1 : NEG * ev1;
        float wa = __expf(ev0), wb = __expf(ev1);
        wsum += wa + wb;
        ax += wa * xa.x + wb * xb.x;
        ay += wa * xa.y + wb * xb.y;
    }
    if (e < dg) {
        int s0 = srcs[base + e];
        float ev = as_[s0 * NH + h] + adv;
        float2 xa = *(const float2*)(x + s0 * NF + fp * 2);
        ev = (ev > 0.f) ? ev : NEG * ev;
        float w = __expf(ev);
        wsum += w;
        ax += w * xa.x;
        ay += w * xa.y;
    }
    float inv = 1.0f / wsum;
    unsigned int pk = (f2bf(ay * inv) << 16) | f2bf(ax * inv);
    sb[d * 64 + h * 8 + fp] = pk;
}

// LDS route-tile accumulation, plain partial-tile flush (no global atomics)
__global__ __launch_bounds__(256) void k_node(const unsigned int* __restrict__ sb,
                                              const int* __restrict__ route,
                                              float* __restrict__ part) {
    __shared__ float tl[PSZ];
    for (int i = threadIdx.x; i < PSZ; i += 256) tl[i] = 0.f;
    __syncthreads();
    const int per = NN / PARTN;              // 625
    int n0 = blockIdx.x * per, n1 = n0 + per;
    int ln = threadIdx.x >> 6, c = threadIdx.x & 63;
    for (int n = n0 + ln; n < n1; n += 4) {
        int r = route[n];
        unsigned int pk = sb[n * 64 + c];
        atomicAdd(&tl[r * 128 + c * 2],     bf2f(pk & 0xffffu));
        atomicAdd(&tl[r * 128 + c * 2 + 1], bf2f(pk >> 16));
        if (c == 0) atomicAdd(&tl[TSZ + r], 1.0f);
    }
    __syncthreads();
    float* pp = part + blockIdx.x * PSZ;
    for (int i = threadIdx.x; i < PSZ; i += 256) pp[i] = tl[i];
}

// sum the 64 partials -> t, cnt (both graphs)
__global__ __launch_bounds__(256) void k_reduce(const float* __restrict__ part,
                                                float* __restrict__ t,
                                                float* __restrict__ cnt) {
    int gid = blockIdx.x * 256 + threadIdx.x;
    if (gid >= 2 * PSZ) return;
    int g = gid / PSZ, i = gid - g * PSZ;
    const float* pp = part + g * PARTN * PSZ + i;
    float s = 0.f;
    for (int b = 0; b < PARTN; ++b) s += pp[b * PSZ];
    if (i < TSZ) t[g * TSZ + i] = s;
    else cnt[g * NR + (i - TSZ)] = s;
}

// fused: agg row (512) from t row, then P[g,i,k] = agg . Wh[:,k]
__global__ __launch_bounds__(256) void k_head(const float* __restrict__ t,
                                              const float* __restrict__ cnt,
                                              const float* __restrict__ W,
                                              const float* __restrict__ bias,
                                              const float* __restrict__ Wh,
                                              float* __restrict__ P) {
    __shared__ float trow[128];
    __shared__ float aggL[512];
    __shared__ float scnt;
    int g = blockIdx.x / NR, i = blockIdx.x - g * NR;
    int tid = threadIdx.x;
    if (tid < 128) trow[tid] = t[(g * NR + i) * 128 + tid];
    if (tid == 0) scnt = cnt[g * NR + i];
    __syncthreads();
    for (int hc = tid; hc < 512; hc += 256) {
        int h = hc >> 6;
        float acc = scnt * bias[hc];
        const float* tp = trow + h * 16;
        for (int f = 0; f < 16; ++f) acc += tp[f] * W[f * 512 + hc];
        aggL[hc] = acc;
    }
    __syncthreads();
    if (tid < 4 * NK) {
        int k = tid >> 2, q = tid & 3;
        const float* wp = Wh + (size_t)(g * 512 + q * 128) * 61 + k;
        const float* ap = aggL + q * 128;
        float acc = 0.f;
        for (int d = 0; d < 128; ++d) acc += ap[d] * wp[d * 61];
        acc += __shfl_down(acc, 1);
        acc += __shfl_down(acc, 2);
        if (q == 0) P[(g * NR + i) * NK + k] = acc;
    }
}

// logits[i,j,k] = P1[i,k]+P2[j,k]+b[k]; global softmax over 62400
__global__ __launch_bounds__(1024) void k_final(const float* __restrict__ P,
                                                const float* __restrict__ bh,
                                                float* __restrict__ out) {
    __shared__ float p1[NR * NK], p2[NR * NK], bsh[NK];
    __shared__ float red[16];
    __shared__ float bc[2];
    int tid = threadIdx.x;
    for (int i = tid; i < NR * NK; i += 1024) { p1[i] = P[i]; p2[i] = P[NR * NK + i]; }
    if (tid < NK) bsh[tid] = bh[tid];
    __syncthreads();
    const int TOT = NR * NR * NK;
    float m = -3.0e38f;
    for (int idx = tid; idx < TOT; idx += 1024) {
        int i = idx / (NR * NK);
        int r = idx - i * (NR * NK);
        int j = r / NK;
        int k = r - j * NK;
        float l = p1[i * NK + k] + p2[j * NK + k] + bsh[k];
        m = fmaxf(m, l);
    }
    for (int off = 32; off > 0; off >>= 1) m = fmaxf(m, __shfl_down(m, off));
    if ((tid & 63) == 0) red[tid >> 6] = m;
    __syncthreads();
    if (tid == 0) {
        float g = red[0];
        for (int w = 1; w < 16; ++w) g = fmaxf(g, red[w]);
        bc[0] = g;
    }
    __syncthreads();
    float gm = bc[0];
    __syncthreads();
    float sum = 0.f;
    for (int idx = tid; idx < TOT; idx += 1024) {
        int i = idx / (NR * NK);
        int r = idx - i * (NR * NK);
        int j = r / NK;
        int k = r - j * NK;
        float l = p1[i * NK + k] + p2[j * NK + k] + bsh[k];
        sum += __expf(l - gm);
    }
    for (int off = 32; off > 0; off >>= 1) sum += __shfl_down(sum, off);
    if ((tid & 63) == 0) red[tid >> 6] = sum;
    __syncthreads();
    if (tid == 0) {
        float g = 0.f;
        for (int w = 0; w < 16; ++w) g += red[w];
        bc[1] = 1.0f / g;
    }
    __syncthreads();
    float inv = bc[1];
    for (int idx = tid; idx < TOT; idx += 1024) {
        int i = idx / (NR * NK);
        int r = idx - i * (NR * NK);
        int j = r / NK;
        int k = r - j * NK;
        float l = p1[i * NK + k] + p2[j * NK + k] + bsh[k];
        out[idx] = __expf(l - gm) * inv;
    }
}

extern "C" void kernel_launch(void* const* d_in, const int* in_sizes, int n_in,
                              void* d_out, int out_size, void* d_ws, size_t ws_size,
                              hipStream_t stream) {
    const float* x1   = (const float*)d_in[0];
    const int*   ei1  = (const int*)d_in[1];
    const int*   rv1  = (const int*)d_in[3];
    const float* x2   = (const float*)d_in[5];
    const int*   ei2  = (const int*)d_in[6];
    const int*   rv2  = (const int*)d_in[8];
    const float* Wg   = (const float*)d_in[10];
    const float* asrc = (const float*)d_in[11];
    const float* adst = (const float*)d_in[12];
    const float* bias = (const float*)d_in[13];
    const float* Wh   = (const float*)d_in[14];
    const float* bh   = (const float*)d_in[15];
    float* out = (float*)d_out;
    float* ws  = (float*)d_ws;

    float* as_  = ws + OFF_AS;
    float* ad_  = ws + OFF_AD;
    float* t    = ws + OFF_T;
    float* cnt  = ws + OFF_CNT;
    float* P    = ws + OFF_P;
    float* part = ws + OFF_PART;
    unsigned int* sb = (unsigned int*)(ws + OFF_S);
    int* ibase  = (int*)(ws + OFF_INT);
    int* gcnt   = ibase + IOFF_GCNT;
    int* deg    = ibase + IOFF_DEG;
    int* start  = ibase + IOFF_START;
    int* cur    = ibase + IOFF_CUR;
    int* srcs   = ibase + IOFF_SRC;

    // zero gcnt[2] + deg[2][NN] (contiguous)
    hipMemsetAsync(gcnt, 0, (size_t)(2 + 2 * NN) * sizeof(int), stream);

    k_a<<<2 * NBLK, 256, 0, stream>>>(x1, x2, Wg, asrc, adst, as_, ad_);
    k_hist<<<(2 * NE + 255) / 256, 256, 0, stream>>>(ei1, ei2, deg);
    k_alloc<<<2 * NBLK, 256, 0, stream>>>(deg, start, cur, gcnt);
    k_scatter<<<(2 * NE + 255) / 256, 256, 0, stream>>>(ei1, ei2, cur, srcs);

    const float* xs[2]  = {x1, x2};
    const int*   rvs[2] = {rv1, rv2};
    for (int g = 0; g < 2; ++g) {
        k_gather<<<NN / 4, 256, 0, stream>>>(start + g * NN, deg + g * NN,
                                             srcs + (size_t)g * NE,
                                             as_ + (size_t)g * NN * NH,
                                             ad_ + (size_t)g * NN * NH,
                                             xs[g], sb);
        k_node<<<PARTN, 256, 0, stream>>>(sb, rvs[g], part + (size_t)g * PARTN * PSZ);
    }
    k_reduce<<<(2 * PSZ + 255) / 256, 256, 0, stream>>>(part, t, cnt);
    k_head<<<2 * NR, 256, 0, stream>>>(t, cnt, Wg, bias, Wh, P);
    k_final<<<1, 1024, 0, stream>>>(P, bh, out);
}

// Round 5
// 249.391 us; speedup vs baseline: 26.1421x; 1.7025x over previous
//
#include <hip/hip_runtime.h>

#define NN 40000      // nodes
#define NE 400000     // edges (before self loops)
#define NF 16         // in features
#define NH 8          // heads
#define NR 40         // routes
#define NK 39         // min(R1,R2)-1 logits kept
#define NEG 0.2f      // leaky relu slope
#define NBLK 157      // (NN+255)/256
#define NCH 16        // chunks per route

// float region offsets
#define OFF_AS   0                        // [2][NN*NH]
#define OFF_AD   (OFF_AS + 2*NN*NH)       // [2][NN*NH]
#define OFF_T    (OFF_AD + 2*NN*NH)       // [2][NR*128]
#define OFF_CNT  (OFF_T + 2*NR*128)       // [2][NR]
#define OFF_P    (OFF_CNT + 2*NR)         // [2][NR*NK]
#define OFF_PART (OFF_P + 2*NR*NK)        // [2][NR][NCH][128]
#define OFF_S    (OFF_PART + 2*NR*NCH*128)// NN*64 uints (2 bf16 each)
#define OFF_INT  (OFF_S + NN*64)
// int region (relative)
#define IOFF_GCNT   0                     // 2
#define IOFF_RHIST  2                     // 2*NR
#define IOFF_DEG    (2 + 2*NR)            // 2*NN
#define IOFF_START  (IOFF_DEG + 2*NN)     // 2*NN
#define IOFF_CUR    (IOFF_START + 2*NN)   // 2*NN
#define IOFF_RSTART (IOFF_CUR + 2*NN)     // 2*NR
#define IOFF_RCUR   (IOFF_RSTART + 2*NR)  // 2*NR
#define IOFF_SRC    (IOFF_RCUR + 2*NR)    // 2*NE
#define IOFF_NID    (IOFF_SRC + 2*NE)     // 2*NN

static __device__ __forceinline__ unsigned int f2bf(float v) {
    unsigned int x = __float_as_uint(v);
    return (x + 0x7FFFu + ((x >> 16) & 1u)) >> 16;   // round-nearest-even
}
static __device__ __forceinline__ float bf2f(unsigned int u) {
    return __uint_as_float(u << 16);
}

// batched: u inline per block, a_s/a_d per node, + LDS route histogram
__global__ __launch_bounds__(256) void k_a(const float* __restrict__ x1,
                                           const float* __restrict__ x2,
                                           const int* __restrict__ rv1,
                                           const int* __restrict__ rv2,
                                           const float* __restrict__ W,
                                           const float* __restrict__ asrc,
                                           const float* __restrict__ adst,
                                           float* __restrict__ as_,
                                           float* __restrict__ ad_,
                                           int* __restrict__ rhist) {
    __shared__ float us[256];
    __shared__ int lh[NR];
    int tid = threadIdx.x;
    if (tid < NR) lh[tid] = 0;
    {
        int tt = tid & 127;
        int f = tt >> 3, h = tt & 7;
        const float* av = (tid < 128 ? asrc : adst) + h * 64;
        const float* wrow = W + f * 512 + h * 64;
        float su = 0.f;
        for (int c = 0; c < 64; ++c) su += wrow[c] * av[c];
        us[tid] = su;      // [0:128) = u_src(f,h), [128:256) = u_dst(f,h)
    }
    __syncthreads();
    int g = blockIdx.x / NBLK;
    int n = (blockIdx.x - g * NBLK) * 256 + tid;
    if (n < NN) {
        const float* x = g ? x2 : x1;
        const int* rv = g ? rv2 : rv1;
        const float4* xp = (const float4*)(x + n * NF);
        float4 v0 = xp[0], v1 = xp[1], v2 = xp[2], v3 = xp[3];
        float xv[16] = {v0.x, v0.y, v0.z, v0.w, v1.x, v1.y, v1.z, v1.w,
                        v2.x, v2.y, v2.z, v2.w, v3.x, v3.y, v3.z, v3.w};
        int o = g * NN * NH + n * NH;
        for (int h = 0; h < NH; ++h) {
            float s1 = 0.f, s2 = 0.f;
            for (int f = 0; f < NF; ++f) {
                s1 += xv[f] * us[f * 8 + h];
                s2 += xv[f] * us[128 + f * 8 + h];
            }
            as_[o + h] = s1;
            ad_[o + h] = s2;
        }
        atomicAdd(&lh[rv[n]], 1);
    }
    __syncthreads();
    if (tid < NR && lh[tid]) atomicAdd(&rhist[g * NR + tid], lh[tid]);
}

// dst-degree histogram, both graphs
__global__ __launch_bounds__(256) void k_hist(const int* __restrict__ ei1,
                                              const int* __restrict__ ei2,
                                              int* __restrict__ deg) {
    int gid = blockIdx.x * 256 + threadIdx.x;
    if (gid >= 2 * NE) return;
    int g = gid >= NE;
    int e = gid - g * NE;
    const int* ei = g ? ei2 : ei1;
    atomicAdd(&deg[g * NN + ei[NE + e]], 1);
}

// bump-allocate contiguous segment per node; 1 global atomic per wave
__global__ __launch_bounds__(256) void k_alloc(const int* __restrict__ deg,
                                               int* __restrict__ start,
                                               int* __restrict__ cur,
                                               int* __restrict__ gcnt) {
    int g = blockIdx.x / NBLK;
    int n = (blockIdx.x - g * NBLK) * 256 + threadIdx.x;
    int d = (n < NN) ? deg[g * NN + n] : 0;
    int lane = threadIdx.x & 63;
    int p = d;
    for (int off = 1; off < 64; off <<= 1) {
        int v = __shfl_up(p, off);
        if (lane >= off) p += v;
    }
    int wavesum = __shfl(p, 63);
    int base = 0;
    if (lane == 63) base = atomicAdd(&gcnt[g], wavesum);
    base = __shfl(base, 63);
    int s = base + p - d;
    if (n < NN) { start[g * NN + n] = s; cur[g * NN + n] = s; }
}

// route segment alloc (trivial: 2 graphs x 40 bins) + cnt as float
__global__ __launch_bounds__(64) void k_ralloc(const int* __restrict__ rhist,
                                               int* __restrict__ rstart,
                                               int* __restrict__ rcur,
                                               float* __restrict__ cnt) {
    int t = threadIdx.x;
    if (t < 2) {
        int run = 0;
        for (int r = 0; r < NR; ++r) {
            int v = rhist[t * NR + r];
            rstart[t * NR + r] = run;
            rcur[t * NR + r] = run;
            cnt[t * NR + r] = (float)v;
            run += v;
        }
    }
}

// scatter src ids into segment order, both graphs
__global__ __launch_bounds__(256) void k_scatter(const int* __restrict__ ei1,
                                                 const int* __restrict__ ei2,
                                                 int* __restrict__ cur,
                                                 int* __restrict__ srcs) {
    int gid = blockIdx.x * 256 + threadIdx.x;
    if (gid >= 2 * NE) return;
    int g = gid >= NE;
    int e = gid - g * NE;
    const int* ei = g ? ei2 : ei1;
    int dstv = ei[NE + e];
    int pos = atomicAdd(&cur[g * NN + dstv], 1);
    srcs[g * NE + pos] = ei[e];
}

// LDS-aggregated counting-sort of node ids by route
__global__ __launch_bounds__(256) void k_nscatter(const int* __restrict__ rv1,
                                                  const int* __restrict__ rv2,
                                                  int* __restrict__ rcur,
                                                  int* __restrict__ nid) {
    __shared__ int lh[NR], lbase[NR];
    int tid = threadIdx.x;
    if (tid < NR) lh[tid] = 0;
    __syncthreads();
    int g = blockIdx.x / NBLK;
    int n = (blockIdx.x - g * NBLK) * 256 + tid;
    const int* rv = g ? rv2 : rv1;
    int r = 0, lpos = 0;
    bool valid = (n < NN);
    if (valid) {
        r = rv[n];
        lpos = atomicAdd(&lh[r], 1);
    }
    __syncthreads();
    if (tid < NR && lh[tid]) lbase[tid] = atomicAdd(&rcur[g * NR + tid], lh[tid]);
    __syncthreads();
    if (valid) nid[g * NN + lbase[r] + lpos] = n;
}

// per dst (64 lanes: h = lane>>3, fp = lane&7 -> float2), edges unrolled x2,
// output packed bf16 pair per lane. Pointers pre-offset per graph.
__global__ __launch_bounds__(256) void k_gather(const int* __restrict__ start,
                                                const int* __restrict__ deg,
                                                const int* __restrict__ srcs,
                                                const float* __restrict__ as_,
                                                const float* __restrict__ ad_,
                                                const float* __restrict__ x,
                                                unsigned int* __restrict__ sb) {
    int d = blockIdx.x * 4 + (threadIdx.x >> 6);
    int lane = threadIdx.x & 63;
    int h = lane >> 3, fp = lane & 7;
    float adv = ad_[d * NH + h];
    float e0 = as_[d * NH + h] + adv;
    e0 = (e0 > 0.f) ? e0 : NEG * e0;
    float w0 = __expf(e0);
    float2 xv = *(const float2*)(x + d * NF + fp * 2);
    float wsum = w0;
    float ax = w0 * xv.x, ay = w0 * xv.y;
    int base = start[d], dg = deg[d];
    int e = 0;
    for (; e + 1 < dg; e += 2) {
        int s0 = srcs[base + e], s1 = srcs[base + e + 1];
        float ev0 = as_[s0 * NH + h] + adv;
        float ev1 = as_[s1 * NH + h] + adv;
        float2 xa = *(const float2*)(x + s0 * NF + fp * 2);
        float2 xb = *(const float2*)(x + s1 * NF + fp * 2);
        ev0 = (ev0 > 0.f) ? ev0 : NEG * ev0;
        ev1 = (ev1 > 0.f) ? ev1 : NEG * ev1;
        float wa = __expf(ev0), wb = __expf(ev1);
        wsum += wa + wb;
        ax += wa * xa.x + wb * xb.x;
        ay += wa * xa.y + wb * xb.y;
    }
    if (e < dg) {
        int s0 = srcs[base + e];
        float ev = as_[s0 * NH + h] + adv;
        float2 xa = *(const float2*)(x + s0 * NF + fp * 2);
        ev = (ev > 0.f) ? ev : NEG * ev;
        float w = __expf(ev);
        wsum += w;
        ax += w * xa.x;
        ay += w * xa.y;
    }
    float inv = 1.0f / wsum;
    unsigned int pk = (f2bf(ay * inv) << 16) | f2bf(ax * inv);
    sb[d * 64 + h * 8 + fp] = pk;
}

// route-sorted register accumulation: block = (g,r,chunk), 4 sub-waves x 64 lanes
__global__ __launch_bounds__(256) void k_rnode(const int* __restrict__ rstart,
                                               const int* __restrict__ rhist,
                                               const int* __restrict__ nid,
                                               const unsigned int* __restrict__ sb,
                                               float* __restrict__ part,
                                               int g) {
    __shared__ float red[4][128];
    int bid = blockIdx.x;
    int r = bid / NCH, ch = bid - r * NCH;
    int seg0 = rstart[g * NR + r];
    int dgr = rhist[g * NR + r];
    int csz = (dgr + NCH - 1) / NCH;
    int a = seg0 + ch * csz;
    int b = seg0 + dgr; { int bb = a + csz; if (bb < b) b = bb; }
    int ln = threadIdx.x >> 6, c = threadIdx.x & 63;
    const int* np = nid + g * NN;
    float sx = 0.f, sy = 0.f;
    for (int i = a + ln; i < b; i += 4) {
        int n = np[i];
        unsigned int pk = sb[n * 64 + c];
        sx += bf2f(pk & 0xffffu);
        sy += bf2f(pk >> 16);
    }
    red[ln][c * 2] = sx;
    red[ln][c * 2 + 1] = sy;
    __syncthreads();
    int tid = threadIdx.x;
    if (tid < 128) {
        float s = red[0][tid] + red[1][tid] + red[2][tid] + red[3][tid];
        part[((g * NR + r) * NCH + ch) * 128 + tid] = s;
    }
}

// sum NCH chunk partials -> t
__global__ __launch_bounds__(256) void k_reduce(const float* __restrict__ part,
                                                float* __restrict__ t) {
    int gid = blockIdx.x * 256 + threadIdx.x;
    if (gid >= 2 * NR * 128) return;
    int gr = gid >> 7, pos = gid & 127;
    const float* pp = part + (gr * NCH) * 128 + pos;
    float s = 0.f;
    for (int chv = 0; chv < NCH; ++chv) s += pp[chv * 128];
    t[gid] = s;
}

// fused: agg row (512) from t row, then P[g,i,k] = agg . Wh[:,k]
__global__ __launch_bounds__(256) void k_head(const float* __restrict__ t,
                                              const float* __restrict__ cnt,
                                              const float* __restrict__ W,
                                              const float* __restrict__ bias,
                                              const float* __restrict__ Wh,
                                              float* __restrict__ P) {
    __shared__ float trow[128];
    __shared__ float aggL[512];
    __shared__ float scnt;
    int g = blockIdx.x / NR, i = blockIdx.x - g * NR;
    int tid = threadIdx.x;
    if (tid < 128) trow[tid] = t[(g * NR + i) * 128 + tid];
    if (tid == 0) scnt = cnt[g * NR + i];
    __syncthreads();
    for (int hc = tid; hc < 512; hc += 256) {
        int h = hc >> 6;
        float acc = scnt * bias[hc];
        const float* tp = trow + h * 16;
        for (int f = 0; f < 16; ++f) acc += tp[f] * W[f * 512 + hc];
        aggL[hc] = acc;
    }
    __syncthreads();
    if (tid < 4 * NK) {
        int k = tid >> 2, q = tid & 3;
        const float* wp = Wh + (size_t)(g * 512 + q * 128) * 61 + k;
        const float* ap = aggL + q * 128;
        float acc = 0.f;
        for (int d = 0; d < 128; ++d) acc += ap[d] * wp[d * 61];
        acc += __shfl_down(acc, 1);
        acc += __shfl_down(acc, 2);
        if (q == 0) P[(g * NR + i) * NK + k] = acc;
    }
}

// logits[i,j,k] = P1[i,k]+P2[j,k]+b[k]; global softmax over 62400
__global__ __launch_bounds__(1024) void k_final(const float* __restrict__ P,
                                                const float* __restrict__ bh,
                                                float* __restrict__ out) {
    __shared__ float p1[NR * NK], p2[NR * NK], bsh[NK];
    __shared__ float red[16];
    __shared__ float bc[2];
    int tid = threadIdx.x;
    for (int i = tid; i < NR * NK; i += 1024) { p1[i] = P[i]; p2[i] = P[NR * NK + i]; }
    if (tid < NK) bsh[tid] = bh[tid];
    __syncthreads();
    const int TOT = NR * NR * NK;
    float m = -3.0e38f;
    for (int idx = tid; idx < TOT; idx += 1024) {
        int i = idx / (NR * NK);
        int r = idx - i * (NR * NK);
        int j = r / NK;
        int k = r - j * NK;
        float l = p1[i * NK + k] + p2[j * NK + k] + bsh[k];
        m = fmaxf(m, l);
    }
    for (int off = 32; off > 0; off >>= 1) m = fmaxf(m, __shfl_down(m, off));
    if ((tid & 63) == 0) red[tid >> 6] = m;
    __syncthreads();
    if (tid == 0) {
        float g = red[0];
        for (int w = 1; w < 16; ++w) g = fmaxf(g, red[w]);
        bc[0] = g;
    }
    __syncthreads();
    float gm = bc[0];
    __syncthreads();
    float sum = 0.f;
    for (int idx = tid; idx < TOT; idx += 1024) {
        int i = idx / (NR * NK);
        int r = idx - i * (NR * NK);
        int j = r / NK;
        int k = r - j * NK;
        float l = p1[i * NK + k] + p2[j * NK + k] + bsh[k];
        sum += __expf(l - gm);
    }
    for (int off = 32; off > 0; off >>= 1) sum += __shfl_down(sum, off);
    if ((tid & 63) == 0) red[tid >> 6] = sum;
    __syncthreads();
    if (tid == 0) {
        float g = 0.f;
        for (int w = 0; w < 16; ++w) g += red[w];
        bc[1] = 1.0f / g;
    }
    __syncthreads();
    float inv = bc[1];
    for (int idx = tid; idx < TOT; idx += 1024) {
        int i = idx / (NR * NK);
        int r = idx - i * (NR * NK);
        int j = r / NK;
        int k = r - j * NK;
        float l = p1[i * NK + k] + p2[j * NK + k] + bsh[k];
        out[idx] = __expf(l - gm) * inv;
    }
}

extern "C" void kernel_launch(void* const* d_in, const int* in_sizes, int n_in,
                              void* d_out, int out_size, void* d_ws, size_t ws_size,
                              hipStream_t stream) {
    const float* x1   = (const float*)d_in[0];
    const int*   ei1  = (const int*)d_in[1];
    const int*   rv1  = (const int*)d_in[3];
    const float* x2   = (const float*)d_in[5];
    const int*   ei2  = (const int*)d_in[6];
    const int*   rv2  = (const int*)d_in[8];
    const float* Wg   = (const float*)d_in[10];
    const float* asrc = (const float*)d_in[11];
    const float* adst = (const float*)d_in[12];
    const float* bias = (const float*)d_in[13];
    const float* Wh   = (const float*)d_in[14];
    const float* bh   = (const float*)d_in[15];
    float* out = (float*)d_out;
    float* ws  = (float*)d_ws;

    float* as_  = ws + OFF_AS;
    float* ad_  = ws + OFF_AD;
    float* t    = ws + OFF_T;
    float* cnt  = ws + OFF_CNT;
    float* P    = ws + OFF_P;
    float* part = ws + OFF_PART;
    unsigned int* sb = (unsigned int*)(ws + OFF_S);
    int* ibase  = (int*)(ws + OFF_INT);
    int* gcnt   = ibase + IOFF_GCNT;
    int* rhist  = ibase + IOFF_RHIST;
    int* deg    = ibase + IOFF_DEG;
    int* start  = ibase + IOFF_START;
    int* cur    = ibase + IOFF_CUR;
    int* rstart = ibase + IOFF_RSTART;
    int* rcur   = ibase + IOFF_RCUR;
    int* srcs   = ibase + IOFF_SRC;
    int* nid    = ibase + IOFF_NID;

    // zero gcnt[2] + rhist[2*NR] + deg[2*NN] (contiguous)
    hipMemsetAsync(gcnt, 0, (size_t)(2 + 2 * NR + 2 * NN) * sizeof(int), stream);

    k_a<<<2 * NBLK, 256, 0, stream>>>(x1, x2, rv1, rv2, Wg, asrc, adst, as_, ad_, rhist);
    k_hist<<<(2 * NE + 255) / 256, 256, 0, stream>>>(ei1, ei2, deg);
    k_alloc<<<2 * NBLK, 256, 0, stream>>>(deg, start, cur, gcnt);
    k_ralloc<<<1, 64, 0, stream>>>(rhist, rstart, rcur, cnt);
    k_scatter<<<(2 * NE + 255) / 256, 256, 0, stream>>>(ei1, ei2, cur, srcs);
    k_nscatter<<<2 * NBLK, 256, 0, stream>>>(rv1, rv2, rcur, nid);

    const float* xs[2] = {x1, x2};
    for (int g = 0; g < 2; ++g) {
        k_gather<<<NN / 4, 256, 0, stream>>>(start + g * NN, deg + g * NN,
                                             srcs + (size_t)g * NE,
                                             as_ + (size_t)g * NN * NH,
                                             ad_ + (size_t)g * NN * NH,
                                             xs[g], sb);
        k_rnode<<<NR * NCH, 256, 0, stream>>>(rstart, rhist, nid, sb, part, g);
    }
    k_reduce<<<(2 * NR * 128 + 255) / 256, 256, 0, stream>>>(part, t);
    k_head<<<2 * NR, 256, 0, stream>>>(t, cnt, Wg, bias, Wh, P);
    k_final<<<1, 1024, 0, stream>>>(P, bh, out);
}

// Round 6
// 182.143 us; speedup vs baseline: 35.7939x; 1.3692x over previous
//
#include <hip/hip_runtime.h>

#define NN 40000      // nodes
#define NE 400000     // edges (before self loops)
#define NF 16         // in features
#define NH 8          // heads
#define NR 40         // routes
#define NK 39         // min(R1,R2)-1 logits kept
#define NEG 0.2f      // leaky relu slope
#define NBLK 157      // (NN+255)/256
#define NCH 16        // chunks per route
#define NB 157        // coarse buckets per graph (dst>>8)
#define SLOT 3328     // entries per bucket slot (mean 2548, +15 sigma)
#define BPG 391       // (NE+1023)/1024 blocks per graph for k_bin

// float region offsets
#define OFF_AS   0                        // [2][NN*NH]
#define OFF_AD   (OFF_AS + 2*NN*NH)       // [2][NN*NH]
#define OFF_T    (OFF_AD + 2*NN*NH)       // [2][NR*128]
#define OFF_CNT  (OFF_T + 2*NR*128)       // [2][NR]
#define OFF_P    (OFF_CNT + 2*NR)         // [2][NR*NK]
#define OFF_PART (OFF_P + 2*NR*NK)        // [2][NR][NCH][128]
#define OFF_S    (OFF_PART + 2*NR*NCH*128)// NN*64 uints (2 bf16 each), reused per graph
#define OFF_INT  (OFF_S + NN*64)
// int region (relative to OFF_INT)
#define IOFF_RHIST  0                       // 2*NR
#define IOFF_BCUR   (2*NR)                  // 2*NB
#define IOFF_RSTART (IOFF_BCUR + 2*NB)      // 2*NR
#define IOFF_RCUR   (IOFF_RSTART + 2*NR)    // 2*NR
#define IOFF_START  (IOFF_RCUR + 2*NR)      // 2*NN (absolute into srcs)
#define IOFF_DEG    (IOFF_START + 2*NN)     // 2*NN
#define IOFF_NID    (IOFF_DEG + 2*NN)       // 2*NN
#define IOFF_BINNED (IOFF_NID + 2*NN)       // 2*NB*SLOT
#define IOFF_SRC    (IOFF_BINNED + 2*NB*SLOT) // 2*NB*SLOT

static __device__ __forceinline__ unsigned int f2bf(float v) {
    unsigned int x = __float_as_uint(v);
    return (x + 0x7FFFu + ((x >> 16) & 1u)) >> 16;   // round-nearest-even
}
static __device__ __forceinline__ float bf2f(unsigned int u) {
    return __uint_as_float(u << 16);
}

// batched: u inline per block, a_s/a_d per node, + LDS route histogram
__global__ __launch_bounds__(256) void k_a(const float* __restrict__ x1,
                                           const float* __restrict__ x2,
                                           const int* __restrict__ rv1,
                                           const int* __restrict__ rv2,
                                           const float* __restrict__ W,
                                           const float* __restrict__ asrc,
                                           const float* __restrict__ adst,
                                           float* __restrict__ as_,
                                           float* __restrict__ ad_,
                                           int* __restrict__ rhist) {
    __shared__ float us[256];
    __shared__ int lh[NR];
    int tid = threadIdx.x;
    if (tid < NR) lh[tid] = 0;
    {
        int tt = tid & 127;
        int f = tt >> 3, h = tt & 7;
        const float* av = (tid < 128 ? asrc : adst) + h * 64;
        const float* wrow = W + f * 512 + h * 64;
        float su = 0.f;
        for (int c = 0; c < 64; ++c) su += wrow[c] * av[c];
        us[tid] = su;      // [0:128) = u_src(f,h), [128:256) = u_dst(f,h)
    }
    __syncthreads();
    int g = blockIdx.x / NBLK;
    int n = (blockIdx.x - g * NBLK) * 256 + tid;
    if (n < NN) {
        const float* x = g ? x2 : x1;
        const int* rv = g ? rv2 : rv1;
        const float4* xp = (const float4*)(x + n * NF);
        float4 v0 = xp[0], v1 = xp[1], v2 = xp[2], v3 = xp[3];
        float xv[16] = {v0.x, v0.y, v0.z, v0.w, v1.x, v1.y, v1.z, v1.w,
                        v2.x, v2.y, v2.z, v2.w, v3.x, v3.y, v3.z, v3.w};
        int o = g * NN * NH + n * NH;
        for (int h = 0; h < NH; ++h) {
            float s1 = 0.f, s2 = 0.f;
            for (int f = 0; f < NF; ++f) {
                s1 += xv[f] * us[f * 8 + h];
                s2 += xv[f] * us[128 + f * 8 + h];
            }
            as_[o + h] = s1;
            ad_[o + h] = s2;
        }
        atomicAdd(&lh[rv[n]], 1);
    }
    __syncthreads();
    if (tid < NR && lh[tid]) atomicAdd(&rhist[g * NR + tid], lh[tid]);
}

// pass 1: coarse-bucket edges, packed (dst<<16)|src, LDS-aggregated cursors
__global__ __launch_bounds__(1024) void k_bin(const int* __restrict__ ei1,
                                              const int* __restrict__ ei2,
                                              int* __restrict__ bcur,
                                              unsigned int* __restrict__ binned) {
    __shared__ int lh[NB], lbase[NB];
    int tid = threadIdx.x;
    int g = blockIdx.x >= BPG;
    int blk = blockIdx.x - g * BPG;
    if (tid < NB) lh[tid] = 0;
    __syncthreads();
    int e = blk * 1024 + tid;
    const int* ei = g ? ei2 : ei1;
    unsigned int v = 0;
    int bin = 0, lpos = 0;
    bool valid = (e < NE);
    if (valid) {
        unsigned int s = (unsigned int)ei[e];
        unsigned int dv = (unsigned int)ei[NE + e];
        v = (dv << 16) | s;
        bin = dv >> 8;
        lpos = atomicAdd(&lh[bin], 1);
    }
    __syncthreads();
    if (tid < NB && lh[tid]) lbase[tid] = atomicAdd(&bcur[g * NB + tid], lh[tid]);
    __syncthreads();
    if (valid) {
        int p = lbase[bin] + lpos;
        if (p < SLOT) binned[(g * NB + bin) * SLOT + p] = v;
    }
}

// pass 2: per (graph,bucket): LDS sort by dst&255 -> sorted srcs + start/deg
__global__ __launch_bounds__(256) void k_fine(const int* __restrict__ bcur,
                                              const unsigned int* __restrict__ binned,
                                              int* __restrict__ start,
                                              int* __restrict__ deg,
                                              int* __restrict__ srcs) {
    __shared__ unsigned int ed[SLOT];
    __shared__ int hist[256], scn[256];
    int tid = threadIdx.x;
    int gb = blockIdx.x;               // 0..2*NB-1
    int g = gb >= NB;
    int b = gb - g * NB;
    int m = bcur[gb]; if (m > SLOT) m = SLOT;
    int base = gb * SLOT;
    for (int i = tid; i < m; i += 256) ed[i] = binned[base + i];
    hist[tid] = 0;
    __syncthreads();
    for (int i = tid; i < m; i += 256) atomicAdd(&hist[(ed[i] >> 16) & 255], 1);
    __syncthreads();
    int v = hist[tid];
    scn[tid] = v;
    __syncthreads();
    for (int off = 1; off < 256; off <<= 1) {
        int u = (tid >= off) ? scn[tid - off] : 0;
        __syncthreads();
        scn[tid] += u;
        __syncthreads();
    }
    int excl = scn[tid] - v;
    int d = b * 256 + tid;
    if (d < NN) { start[g * NN + d] = base + excl; deg[g * NN + d] = v; }
    hist[tid] = excl;                  // reuse as cursor
    __syncthreads();
    for (int i = tid; i < m; i += 256) {
        unsigned int e = ed[i];
        int ld = (e >> 16) & 255;
        int pos = atomicAdd(&hist[ld], 1);
        srcs[base + pos] = (int)(e & 0xffffu);
    }
}

// route segment alloc (trivial: 2 graphs x 40 bins) + cnt as float
__global__ __launch_bounds__(64) void k_ralloc(const int* __restrict__ rhist,
                                               int* __restrict__ rstart,
                                               int* __restrict__ rcur,
                                               float* __restrict__ cnt) {
    int t = threadIdx.x;
    if (t < 2) {
        int run = 0;
        for (int r = 0; r < NR; ++r) {
            int v = rhist[t * NR + r];
            rstart[t * NR + r] = run;
            rcur[t * NR + r] = run;
            cnt[t * NR + r] = (float)v;
            run += v;
        }
    }
}

// LDS-aggregated counting-sort of node ids by route
__global__ __launch_bounds__(256) void k_nscatter(const int* __restrict__ rv1,
                                                  const int* __restrict__ rv2,
                                                  int* __restrict__ rcur,
                                                  int* __restrict__ nid) {
    __shared__ int lh[NR], lbase[NR];
    int tid = threadIdx.x;
    if (tid < NR) lh[tid] = 0;
    __syncthreads();
    int g = blockIdx.x / NBLK;
    int n = (blockIdx.x - g * NBLK) * 256 + tid;
    const int* rv = g ? rv2 : rv1;
    int r = 0, lpos = 0;
    bool valid = (n < NN);
    if (valid) {
        r = rv[n];
        lpos = atomicAdd(&lh[r], 1);
    }
    __syncthreads();
    if (tid < NR && lh[tid]) lbase[tid] = atomicAdd(&rcur[g * NR + tid], lh[tid]);
    __syncthreads();
    if (valid) nid[g * NN + lbase[r] + lpos] = n;
}

// per dst (64 lanes: h = lane>>3, fp = lane&7 -> float2), edges unrolled x2,
// output packed bf16 pair per lane. start/deg/as_/ad_ pre-offset per graph;
// srcs absolute (start holds absolute indices).
__global__ __launch_bounds__(256) void k_gather(const int* __restrict__ start,
                                                const int* __restrict__ deg,
                                                const int* __restrict__ srcs,
                                                const float* __restrict__ as_,
                                                const float* __restrict__ ad_,
                                                const float* __restrict__ x,
                                                unsigned int* __restrict__ sb) {
    int d = blockIdx.x * 4 + (threadIdx.x >> 6);
    int lane = threadIdx.x & 63;
    int h = lane >> 3, fp = lane & 7;
    float adv = ad_[d * NH + h];
    float e0 = as_[d * NH + h] + adv;
    e0 = (e0 > 0.f) ? e0 : NEG * e0;
    float w0 = __expf(e0);
    float2 xv = *(const float2*)(x + d * NF + fp * 2);
    float wsum = w0;
    float ax = w0 * xv.x, ay = w0 * xv.y;
    int base = start[d], dg = deg[d];
    int e = 0;
    for (; e + 1 < dg; e += 2) {
        int s0 = srcs[base + e], s1 = srcs[base + e + 1];
        float ev0 = as_[s0 * NH + h] + adv;
        float ev1 = as_[s1 * NH + h] + adv;
        float2 xa = *(const float2*)(x + s0 * NF + fp * 2);
        float2 xb = *(const float2*)(x + s1 * NF + fp * 2);
        ev0 = (ev0 > 0.f) ? ev0 : NEG * ev0;
        ev1 = (ev1 > 0.f) ? ev1 : NEG * ev1;
        float wa = __expf(ev0), wb = __expf(ev1);
        wsum += wa + wb;
        ax += wa * xa.x + wb * xb.x;
        ay += wa * xa.y + wb * xb.y;
    }
    if (e < dg) {
        int s0 = srcs[base + e];
        float ev = as_[s0 * NH + h] + adv;
        float2 xa = *(const float2*)(x + s0 * NF + fp * 2);
        ev = (ev > 0.f) ? ev : NEG * ev;
        float w = __expf(ev);
        wsum += w;
        ax += w * xa.x;
        ay += w * xa.y;
    }
    float inv = 1.0f / wsum;
    unsigned int pk = (f2bf(ay * inv) << 16) | f2bf(ax * inv);
    sb[d * 64 + h * 8 + fp] = pk;
}

// route-sorted register accumulation: block = (r,chunk), 4 sub-waves x 64 lanes
__global__ __launch_bounds__(256) void k_rnode(const int* __restrict__ rstart,
                                               const int* __restrict__ rhist,
                                               const int* __restrict__ nid,
                                               const unsigned int* __restrict__ sb,
                                               float* __restrict__ part,
                                               int g) {
    __shared__ float red[4][128];
    int bid = blockIdx.x;
    int r = bid / NCH, ch = bid - r * NCH;
    int seg0 = rstart[g * NR + r];
    int dgr = rhist[g * NR + r];
    int csz = (dgr + NCH - 1) / NCH;
    int a = seg0 + ch * csz;
    int b = seg0 + dgr; { int bb = a + csz; if (bb < b) b = bb; }
    int ln = threadIdx.x >> 6, c = threadIdx.x & 63;
    const int* np = nid + g * NN;
    float sx = 0.f, sy = 0.f;
    for (int i = a + ln; i < b; i += 4) {
        int n = np[i];
        unsigned int pk = sb[n * 64 + c];
        sx += bf2f(pk & 0xffffu);
        sy += bf2f(pk >> 16);
    }
    red[ln][c * 2] = sx;
    red[ln][c * 2 + 1] = sy;
    __syncthreads();
    int tid = threadIdx.x;
    if (tid < 128) {
        float s = red[0][tid] + red[1][tid] + red[2][tid] + red[3][tid];
        part[((g * NR + r) * NCH + ch) * 128 + tid] = s;
    }
}

// sum NCH chunk partials -> t
__global__ __launch_bounds__(256) void k_reduce(const float* __restrict__ part,
                                                float* __restrict__ t) {
    int gid = blockIdx.x * 256 + threadIdx.x;
    if (gid >= 2 * NR * 128) return;
    int gr = gid >> 7, pos = gid & 127;
    const float* pp = part + (gr * NCH) * 128 + pos;
    float s = 0.f;
    for (int chv = 0; chv < NCH; ++chv) s += pp[chv * 128];
    t[gid] = s;
}

// fused: agg row (512) from t row, then P[g,i,k] = agg . Wh[:,k]
__global__ __launch_bounds__(256) void k_head(const float* __restrict__ t,
                                              const float* __restrict__ cnt,
                                              const float* __restrict__ W,
                                              const float* __restrict__ bias,
                                              const float* __restrict__ Wh,
                                              float* __restrict__ P) {
    __shared__ float trow[128];
    __shared__ float aggL[512];
    __shared__ float scnt;
    int g = blockIdx.x / NR, i = blockIdx.x - g * NR;
    int tid = threadIdx.x;
    if (tid < 128) trow[tid] = t[(g * NR + i) * 128 + tid];
    if (tid == 0) scnt = cnt[g * NR + i];
    __syncthreads();
    for (int hc = tid; hc < 512; hc += 256) {
        int h = hc >> 6;
        float acc = scnt * bias[hc];
        const float* tp = trow + h * 16;
        for (int f = 0; f < 16; ++f) acc += tp[f] * W[f * 512 + hc];
        aggL[hc] = acc;
    }
    __syncthreads();
    if (tid < 4 * NK) {
        int k = tid >> 2, q = tid & 3;
        const float* wp = Wh + (size_t)(g * 512 + q * 128) * 61 + k;
        const float* ap = aggL + q * 128;
        float acc = 0.f;
        for (int d = 0; d < 128; ++d) acc += ap[d] * wp[d * 61];
        acc += __shfl_down(acc, 1);
        acc += __shfl_down(acc, 2);
        if (q == 0) P[(g * NR + i) * NK + k] = acc;
    }
}

// logits[i,j,k] = P1[i,k]+P2[j,k]+b[k]; global softmax over 62400
__global__ __launch_bounds__(1024) void k_final(const float* __restrict__ P,
                                                const float* __restrict__ bh,
                                                float* __restrict__ out) {
    __shared__ float p1[NR * NK], p2[NR * NK], bsh[NK];
    __shared__ float red[16];
    __shared__ float bc[2];
    int tid = threadIdx.x;
    for (int i = tid; i < NR * NK; i += 1024) { p1[i] = P[i]; p2[i] = P[NR * NK + i]; }
    if (tid < NK) bsh[tid] = bh[tid];
    __syncthreads();
    const int TOT = NR * NR * NK;
    float m = -3.0e38f;
    for (int idx = tid; idx < TOT; idx += 1024) {
        int i = idx / (NR * NK);
        int r = idx - i * (NR * NK);
        int j = r / NK;
        int k = r - j * NK;
        float l = p1[i * NK + k] + p2[j * NK + k] + bsh[k];
        m = fmaxf(m, l);
    }
    for (int off = 32; off > 0; off >>= 1) m = fmaxf(m, __shfl_down(m, off));
    if ((tid & 63) == 0) red[tid >> 6] = m;
    __syncthreads();
    if (tid == 0) {
        float g = red[0];
        for (int w = 1; w < 16; ++w) g = fmaxf(g, red[w]);
        bc[0] = g;
    }
    __syncthreads();
    float gm = bc[0];
    __syncthreads();
    float sum = 0.f;
    for (int idx = tid; idx < TOT; idx += 1024) {
        int i = idx / (NR * NK);
        int r = idx - i * (NR * NK);
        int j = r / NK;
        int k = r - j * NK;
        float l = p1[i * NK + k] + p2[j * NK + k] + bsh[k];
        sum += __expf(l - gm);
    }
    for (int off = 32; off > 0; off >>= 1) sum += __shfl_down(sum, off);
    if ((tid & 63) == 0) red[tid >> 6] = sum;
    __syncthreads();
    if (tid == 0) {
        float g = 0.f;
        for (int w = 0; w < 16; ++w) g += red[w];
        bc[1] = 1.0f / g;
    }
    __syncthreads();
    float inv = bc[1];
    for (int idx = tid; idx < TOT; idx += 1024) {
        int i = idx / (NR * NK);
        int r = idx - i * (NR * NK);
        int j = r / NK;
        int k = r - j * NK;
        float l = p1[i * NK + k] + p2[j * NK + k] + bsh[k];
        out[idx] = __expf(l - gm) * inv;
    }
}

extern "C" void kernel_launch(void* const* d_in, const int* in_sizes, int n_in,
                              void* d_out, int out_size, void* d_ws, size_t ws_size,
                              hipStream_t stream) {
    const float* x1   = (const float*)d_in[0];
    const int*   ei1  = (const int*)d_in[1];
    const int*   rv1  = (const int*)d_in[3];
    const float* x2   = (const float*)d_in[5];
    const int*   ei2  = (const int*)d_in[6];
    const int*   rv2  = (const int*)d_in[8];
    const float* Wg   = (const float*)d_in[10];
    const float* asrc = (const float*)d_in[11];
    const float* adst = (const float*)d_in[12];
    const float* bias = (const float*)d_in[13];
    const float* Wh   = (const float*)d_in[14];
    const float* bh   = (const float*)d_in[15];
    float* out = (float*)d_out;
    float* ws  = (float*)d_ws;

    float* as_  = ws + OFF_AS;
    float* ad_  = ws + OFF_AD;
    float* t    = ws + OFF_T;
    float* cnt  = ws + OFF_CNT;
    float* P    = ws + OFF_P;
    float* part = ws + OFF_PART;
    unsigned int* sb = (unsigned int*)(ws + OFF_S);
    int* ibase  = (int*)(ws + OFF_INT);
    int* rhist  = ibase + IOFF_RHIST;
    int* bcur   = ibase + IOFF_BCUR;
    int* rstart = ibase + IOFF_RSTART;
    int* rcur   = ibase + IOFF_RCUR;
    int* start  = ibase + IOFF_START;
    int* deg    = ibase + IOFF_DEG;
    int* nid    = ibase + IOFF_NID;
    unsigned int* binned = (unsigned int*)(ibase + IOFF_BINNED);
    int* srcs   = ibase + IOFF_SRC;

    // zero rhist[2*NR] + bcur[2*NB] (contiguous)
    hipMemsetAsync(rhist, 0, (size_t)(2 * NR + 2 * NB) * sizeof(int), stream);

    k_a<<<2 * NBLK, 256, 0, stream>>>(x1, x2, rv1, rv2, Wg, asrc, adst, as_, ad_, rhist);
    k_bin<<<2 * BPG, 1024, 0, stream>>>(ei1, ei2, bcur, binned);
    k_ralloc<<<1, 64, 0, stream>>>(rhist, rstart, rcur, cnt);
    k_fine<<<2 * NB, 256, 0, stream>>>(bcur, binned, start, deg, srcs);
    k_nscatter<<<2 * NBLK, 256, 0, stream>>>(rv1, rv2, rcur, nid);

    const float* xs[2] = {x1, x2};
    for (int g = 0; g < 2; ++g) {
        k_gather<<<NN / 4, 256, 0, stream>>>(start + g * NN, deg + g * NN, srcs,
                                             as_ + (size_t)g * NN * NH,
                                             ad_ + (size_t)g * NN * NH,
                                             xs[g], sb);
        k_rnode<<<NR * NCH, 256, 0, stream>>>(rstart, rhist, nid, sb, part, g);
    }
    k_reduce<<<(2 * NR * 128 + 255) / 256, 256, 0, stream>>>(part, t);
    k_head<<<2 * NR, 256, 0, stream>>>(t, cnt, Wg, bias, Wh, P);
    k_final<<<1, 1024, 0, stream>>>(P, bh, out);
}

// Round 7
// 154.405 us; speedup vs baseline: 42.2242x; 1.1797x over previous
//
#include <hip/hip_runtime.h>

#define NN 40000      // nodes
#define NE 400000     // edges (before self loops)
#define NF 16         // in features
#define NH 8          // heads
#define NR 40         // routes
#define NK 39         // min(R1,R2)-1 logits kept
#define NEG 0.2f      // leaky relu slope
#define NBLK 157      // (NN+255)/256
#define NCH 16        // chunks per route
#define NB 157        // coarse buckets per graph (dst>>8)
#define SLOT 3328     // entries per bucket slot (mean 2560, +15 sigma)
#define BPG 391       // (NE+1023)/1024 blocks per graph for k_bin

// float region offsets
#define OFF_AS   0                        // [2][NN*NH]
#define OFF_AD   (OFF_AS + 2*NN*NH)       // [2][NN*NH]
#define OFF_CNT  (OFF_AD + 2*NN*NH)       // [2][NR]
#define OFF_P    (OFF_CNT + 2*NR)         // [2][NR*NK]
#define OFF_PART (OFF_P + 2*NR*NK)        // [2][NR][NCH][128]
#define OFF_S    (OFF_PART + 2*NR*NCH*128)// [2][NN*64] uints (2 bf16 each)
#define OFF_INT  (OFF_S + 2*NN*64)
// int region (relative to OFF_INT)
#define IOFF_RHIST  0                       // 2*NR
#define IOFF_BCUR   (2*NR)                  // 2*NB   (rhist+bcur zeroed together: 394)
#define IOFF_RSTART (IOFF_BCUR + 2*NB)      // 2*NR
#define IOFF_RCUR   (IOFF_RSTART + 2*NR)    // 2*NR
#define IOFF_START  (IOFF_RCUR + 2*NR)      // 2*NN (absolute into srcs)
#define IOFF_DEG    (IOFF_START + 2*NN)     // 2*NN
#define IOFF_NID    (IOFF_DEG + 2*NN)       // 2*NN
#define IOFF_BINNED (IOFF_NID + 2*NN)       // 2*NB*SLOT
#define IOFF_SRC    (IOFF_BINNED + 2*NB*SLOT) // 2*NB*SLOT

static __device__ __forceinline__ unsigned int f2bf(float v) {
    unsigned int x = __float_as_uint(v);
    return (x + 0x7FFFu + ((x >> 16) & 1u)) >> 16;   // round-nearest-even
}
static __device__ __forceinline__ float bf2f(unsigned int u) {
    return __uint_as_float(u << 16);
}

// zero the two atomic-counter arrays (replaces hipMemsetAsync's fill kernel)
__global__ __launch_bounds__(512) void k_zero(int* __restrict__ p) {
    int i = threadIdx.x;
    if (i < 2 * NR + 2 * NB) p[i] = 0;
}

// batched: u inline per block, a_s/a_d per node, + LDS route histogram
__global__ __launch_bounds__(256) void k_a(const float* __restrict__ x1,
                                           const float* __restrict__ x2,
                                           const int* __restrict__ rv1,
                                           const int* __restrict__ rv2,
                                           const float* __restrict__ W,
                                           const float* __restrict__ asrc,
                                           const float* __restrict__ adst,
                                           float* __restrict__ as_,
                                           float* __restrict__ ad_,
                                           int* __restrict__ rhist) {
    __shared__ float us[256];
    __shared__ int lh[NR];
    int tid = threadIdx.x;
    if (tid < NR) lh[tid] = 0;
    {
        int tt = tid & 127;
        int f = tt >> 3, h = tt & 7;
        const float* av = (tid < 128 ? asrc : adst) + h * 64;
        const float* wrow = W + f * 512 + h * 64;
        float su = 0.f;
        for (int c = 0; c < 64; ++c) su += wrow[c] * av[c];
        us[tid] = su;      // [0:128) = u_src(f,h), [128:256) = u_dst(f,h)
    }
    __syncthreads();
    int g = blockIdx.x / NBLK;
    int n = (blockIdx.x - g * NBLK) * 256 + tid;
    if (n < NN) {
        const float* x = g ? x2 : x1;
        const int* rv = g ? rv2 : rv1;
        const float4* xp = (const float4*)(x + n * NF);
        float4 v0 = xp[0], v1 = xp[1], v2 = xp[2], v3 = xp[3];
        float xv[16] = {v0.x, v0.y, v0.z, v0.w, v1.x, v1.y, v1.z, v1.w,
                        v2.x, v2.y, v2.z, v2.w, v3.x, v3.y, v3.z, v3.w};
        int o = g * NN * NH + n * NH;
        for (int h = 0; h < NH; ++h) {
            float s1 = 0.f, s2 = 0.f;
            for (int f = 0; f < NF; ++f) {
                s1 += xv[f] * us[f * 8 + h];
                s2 += xv[f] * us[128 + f * 8 + h];
            }
            as_[o + h] = s1;
            ad_[o + h] = s2;
        }
        atomicAdd(&lh[rv[n]], 1);
    }
    __syncthreads();
    if (tid < NR && lh[tid]) atomicAdd(&rhist[g * NR + tid], lh[tid]);
}

// pass 1: coarse-bucket edges, packed (dst<<16)|src, LDS-aggregated cursors
__global__ __launch_bounds__(1024) void k_bin(const int* __restrict__ ei1,
                                              const int* __restrict__ ei2,
                                              int* __restrict__ bcur,
                                              unsigned int* __restrict__ binned) {
    __shared__ int lh[NB], lbase[NB];
    int tid = threadIdx.x;
    int g = blockIdx.x >= BPG;
    int blk = blockIdx.x - g * BPG;
    if (tid < NB) lh[tid] = 0;
    __syncthreads();
    int e = blk * 1024 + tid;
    const int* ei = g ? ei2 : ei1;
    unsigned int v = 0;
    int bin = 0, lpos = 0;
    bool valid = (e < NE);
    if (valid) {
        unsigned int s = (unsigned int)ei[e];
        unsigned int dv = (unsigned int)ei[NE + e];
        v = (dv << 16) | s;
        bin = dv >> 8;
        lpos = atomicAdd(&lh[bin], 1);
    }
    __syncthreads();
    if (tid < NB && lh[tid]) lbase[tid] = atomicAdd(&bcur[g * NB + tid], lh[tid]);
    __syncthreads();
    if (valid) {
        int p = lbase[bin] + lpos;
        if (p < SLOT) binned[(g * NB + bin) * SLOT + p] = v;
    }
}

// pass 2: per (graph,bucket): LDS sort by dst&255 -> sorted srcs + start/deg
__global__ __launch_bounds__(256) void k_fine(const int* __restrict__ bcur,
                                              const unsigned int* __restrict__ binned,
                                              int* __restrict__ start,
                                              int* __restrict__ deg,
                                              int* __restrict__ srcs) {
    __shared__ unsigned int ed[SLOT];
    __shared__ int hist[256], scn[256];
    int tid = threadIdx.x;
    int gb = blockIdx.x;               // 0..2*NB-1
    int g = gb >= NB;
    int b = gb - g * NB;
    int m = bcur[gb]; if (m > SLOT) m = SLOT;
    int base = gb * SLOT;
    for (int i = tid; i < m; i += 256) ed[i] = binned[base + i];
    hist[tid] = 0;
    __syncthreads();
    for (int i = tid; i < m; i += 256) atomicAdd(&hist[(ed[i] >> 16) & 255], 1);
    __syncthreads();
    int v = hist[tid];
    scn[tid] = v;
    __syncthreads();
    for (int off = 1; off < 256; off <<= 1) {
        int u = (tid >= off) ? scn[tid - off] : 0;
        __syncthreads();
        scn[tid] += u;
        __syncthreads();
    }
    int excl = scn[tid] - v;
    int d = b * 256 + tid;
    if (d < NN) { start[g * NN + d] = base + excl; deg[g * NN + d] = v; }
    hist[tid] = excl;                  // reuse as cursor
    __syncthreads();
    for (int i = tid; i < m; i += 256) {
        unsigned int e = ed[i];
        int ld = (e >> 16) & 255;
        int pos = atomicAdd(&hist[ld], 1);
        srcs[base + pos] = (int)(e & 0xffffu);
    }
}

// route segment alloc (trivial: 2 graphs x 40 bins) + cnt as float
__global__ __launch_bounds__(64) void k_ralloc(const int* __restrict__ rhist,
                                               int* __restrict__ rstart,
                                               int* __restrict__ rcur,
                                               float* __restrict__ cnt) {
    int t = threadIdx.x;
    if (t < 2) {
        int run = 0;
        for (int r = 0; r < NR; ++r) {
            int v = rhist[t * NR + r];
            rstart[t * NR + r] = run;
            rcur[t * NR + r] = run;
            cnt[t * NR + r] = (float)v;
            run += v;
        }
    }
}

// LDS-aggregated counting-sort of node ids by route
__global__ __launch_bounds__(256) void k_nscatter(const int* __restrict__ rv1,
                                                  const int* __restrict__ rv2,
                                                  int* __restrict__ rcur,
                                                  int* __restrict__ nid) {
    __shared__ int lh[NR], lbase[NR];
    int tid = threadIdx.x;
    if (tid < NR) lh[tid] = 0;
    __syncthreads();
    int g = blockIdx.x / NBLK;
    int n = (blockIdx.x - g * NBLK) * 256 + tid;
    const int* rv = g ? rv2 : rv1;
    int r = 0, lpos = 0;
    bool valid = (n < NN);
    if (valid) {
        r = rv[n];
        lpos = atomicAdd(&lh[r], 1);
    }
    __syncthreads();
    if (tid < NR && lh[tid]) lbase[tid] = atomicAdd(&rcur[g * NR + tid], lh[tid]);
    __syncthreads();
    if (valid) nid[g * NN + lbase[r] + lpos] = n;
}

// both graphs in one dispatch; per dst a 64-lane wave (h=lane>>3, fp=lane&7),
// 4 independent edge chains in flight; packed bf16 output.
__global__ __launch_bounds__(256) void k_gather(const int* __restrict__ start,
                                                const int* __restrict__ deg,
                                                const int* __restrict__ srcs,
                                                const float* __restrict__ as_,
                                                const float* __restrict__ ad_,
                                                const float* __restrict__ x1,
                                                const float* __restrict__ x2,
                                                unsigned int* __restrict__ sb) {
    int idx = blockIdx.x * 4 + (threadIdx.x >> 6);   // 0..2*NN-1
    int g = idx >= NN;
    int d = idx - g * NN;
    const float* x = g ? x2 : x1;
    const float* asg = as_ + (size_t)g * NN * NH;
    int lane = threadIdx.x & 63;
    int h = lane >> 3, fp = lane & 7;
    float adv = ad_[(size_t)g * NN * NH + d * NH + h];
    float e0 = asg[d * NH + h] + adv;
    e0 = (e0 > 0.f) ? e0 : NEG * e0;
    float w0 = __expf(e0);
    float2 xv = *(const float2*)(x + d * NF + fp * 2);
    float wsum = w0;
    float ax = w0 * xv.x, ay = w0 * xv.y;
    int base = start[idx], dg = deg[idx];
    int e = 0;
    for (; e + 3 < dg; e += 4) {
        int s0 = srcs[base + e], s1 = srcs[base + e + 1];
        int s2 = srcs[base + e + 2], s3 = srcs[base + e + 3];
        float ev0 = asg[s0 * NH + h] + adv;
        float ev1 = asg[s1 * NH + h] + adv;
        float ev2 = asg[s2 * NH + h] + adv;
        float ev3 = asg[s3 * NH + h] + adv;
        float2 xa = *(const float2*)(x + s0 * NF + fp * 2);
        float2 xb = *(const float2*)(x + s1 * NF + fp * 2);
        float2 xc = *(const float2*)(x + s2 * NF + fp * 2);
        float2 xd = *(const float2*)(x + s3 * NF + fp * 2);
        ev0 = (ev0 > 0.f) ? ev0 : NEG * ev0;
        ev1 = (ev1 > 0.f) ? ev1 : NEG * ev1;
        ev2 = (ev2 > 0.f) ? ev2 : NEG * ev2;
        ev3 = (ev3 > 0.f) ? ev3 : NEG * ev3;
        float wa = __expf(ev0), wb = __expf(ev1);
        float wc = __expf(ev2), wd = __expf(ev3);
        wsum += (wa + wb) + (wc + wd);
        ax += wa * xa.x + wb * xb.x + wc * xc.x + wd * xd.x;
        ay += wa * xa.y + wb * xb.y + wc * xc.y + wd * xd.y;
    }
    for (; e < dg; ++e) {
        int s0 = srcs[base + e];
        float ev = asg[s0 * NH + h] + adv;
        float2 xa = *(const float2*)(x + s0 * NF + fp * 2);
        ev = (ev > 0.f) ? ev : NEG * ev;
        float w = __expf(ev);
        wsum += w;
        ax += w * xa.x;
        ay += w * xa.y;
    }
    float inv = 1.0f / wsum;
    unsigned int pk = (f2bf(ay * inv) << 16) | f2bf(ax * inv);
    sb[(size_t)idx * 64 + h * 8 + fp] = pk;
}

// both graphs in one dispatch: block = (g,r,chunk), 4 sub-waves x 64 lanes
__global__ __launch_bounds__(256) void k_rnode(const int* __restrict__ rstart,
                                               const int* __restrict__ rhist,
                                               const int* __restrict__ nid,
                                               const unsigned int* __restrict__ sb,
                                               float* __restrict__ part) {
    __shared__ float red[4][128];
    int g = blockIdx.x >= NR * NCH;
    int bid = blockIdx.x - g * NR * NCH;
    int r = bid / NCH, ch = bid - r * NCH;
    int seg0 = rstart[g * NR + r];
    int dgr = rhist[g * NR + r];
    int csz = (dgr + NCH - 1) / NCH;
    int a = seg0 + ch * csz;
    int b = seg0 + dgr; { int bb = a + csz; if (bb < b) b = bb; }
    int ln = threadIdx.x >> 6, c = threadIdx.x & 63;
    const int* np = nid + g * NN;
    const unsigned int* sg = sb + (size_t)g * NN * 64;
    float sx = 0.f, sy = 0.f;
    for (int i = a + ln; i < b; i += 4) {
        int n = np[i];
        unsigned int pk = sg[(size_t)n * 64 + c];
        sx += bf2f(pk & 0xffffu);
        sy += bf2f(pk >> 16);
    }
    red[ln][c * 2] = sx;
    red[ln][c * 2 + 1] = sy;
    __syncthreads();
    int tid = threadIdx.x;
    if (tid < 128) {
        float s = red[0][tid] + red[1][tid] + red[2][tid] + red[3][tid];
        part[((g * NR + r) * NCH + ch) * 128 + tid] = s;
    }
}

// fused: chunk-partial reduce -> t row -> agg row (512) -> P[g,i,k]
__global__ __launch_bounds__(256) void k_head(const float* __restrict__ part,
                                              const float* __restrict__ cnt,
                                              const float* __restrict__ W,
                                              const float* __restrict__ bias,
                                              const float* __restrict__ Wh,
                                              float* __restrict__ P) {
    __shared__ float trow[128];
    __shared__ float aggL[512];
    __shared__ float scnt;
    int g = blockIdx.x / NR, i = blockIdx.x - g * NR;
    int tid = threadIdx.x;
    if (tid < 128) {
        const float* pp = part + ((g * NR + i) * NCH) * 128 + tid;
        float s = 0.f;
        for (int ch = 0; ch < NCH; ++ch) s += pp[ch * 128];
        trow[tid] = s;
    }
    if (tid == 0) scnt = cnt[g * NR + i];
    __syncthreads();
    for (int hc = tid; hc < 512; hc += 256) {
        int h = hc >> 6;
        float acc = scnt * bias[hc];
        const float* tp = trow + h * 16;
        for (int f = 0; f < 16; ++f) acc += tp[f] * W[f * 512 + hc];
        aggL[hc] = acc;
    }
    __syncthreads();
    if (tid < 4 * NK) {
        int k = tid >> 2, q = tid & 3;
        const float* wp = Wh + (size_t)(g * 512 + q * 128) * 61 + k;
        const float* ap = aggL + q * 128;
        float acc = 0.f;
        for (int d = 0; d < 128; ++d) acc += ap[d] * wp[d * 61];
        acc += __shfl_down(acc, 1);
        acc += __shfl_down(acc, 2);
        if (q == 0) P[(g * NR + i) * NK + k] = acc;
    }
}

// logits[i,j,k] = P1[i,k]+P2[j,k]+b[k]; global softmax over 62400
__global__ __launch_bounds__(1024) void k_final(const float* __restrict__ P,
                                                const float* __restrict__ bh,
                                                float* __restrict__ out) {
    __shared__ float p1[NR * NK], p2[NR * NK], bsh[NK];
    __shared__ float red[16];
    __shared__ float bc[2];
    int tid = threadIdx.x;
    for (int i = tid; i < NR * NK; i += 1024) { p1[i] = P[i]; p2[i] = P[NR * NK + i]; }
    if (tid < NK) bsh[tid] = bh[tid];
    __syncthreads();
    const int TOT = NR * NR * NK;
    float m = -3.0e38f;
    for (int idx = tid; idx < TOT; idx += 1024) {
        int i = idx / (NR * NK);
        int r = idx - i * (NR * NK);
        int j = r / NK;
        int k = r - j * NK;
        float l = p1[i * NK + k] + p2[j * NK + k] + bsh[k];
        m = fmaxf(m, l);
    }
    for (int off = 32; off > 0; off >>= 1) m = fmaxf(m, __shfl_down(m, off));
    if ((tid & 63) == 0) red[tid >> 6] = m;
    __syncthreads();
    if (tid == 0) {
        float g = red[0];
        for (int w = 1; w < 16; ++w) g = fmaxf(g, red[w]);
        bc[0] = g;
    }
    __syncthreads();
    float gm = bc[0];
    __syncthreads();
    float sum = 0.f;
    for (int idx = tid; idx < TOT; idx += 1024) {
        int i = idx / (NR * NK);
        int r = idx - i * (NR * NK);
        int j = r / NK;
        int k = r - j * NK;
        float l = p1[i * NK + k] + p2[j * NK + k] + bsh[k];
        sum += __expf(l - gm);
    }
    for (int off = 32; off > 0; off >>= 1) sum += __shfl_down(sum, off);
    if ((tid & 63) == 0) red[tid >> 6] = sum;
    __syncthreads();
    if (tid == 0) {
        float g = 0.f;
        for (int w = 0; w < 16; ++w) g += red[w];
        bc[1] = 1.0f / g;
    }
    __syncthreads();
    float inv = bc[1];
    for (int idx = tid; idx < TOT; idx += 1024) {
        int i = idx / (NR * NK);
        int r = idx - i * (NR * NK);
        int j = r / NK;
        int k = r - j * NK;
        float l = p1[i * NK + k] + p2[j * NK + k] + bsh[k];
        out[idx] = __expf(l - gm) * inv;
    }
}

extern "C" void kernel_launch(void* const* d_in, const int* in_sizes, int n_in,
                              void* d_out, int out_size, void* d_ws, size_t ws_size,
                              hipStream_t stream) {
    const float* x1   = (const float*)d_in[0];
    const int*   ei1  = (const int*)d_in[1];
    const int*   rv1  = (const int*)d_in[3];
    const float* x2   = (const float*)d_in[5];
    const int*   ei2  = (const int*)d_in[6];
    const int*   rv2  = (const int*)d_in[8];
    const float* Wg   = (const float*)d_in[10];
    const float* asrc = (const float*)d_in[11];
    const float* adst = (const float*)d_in[12];
    const float* bias = (const float*)d_in[13];
    const float* Wh   = (const float*)d_in[14];
    const float* bh   = (const float*)d_in[15];
    float* out = (float*)d_out;
    float* ws  = (float*)d_ws;

    float* as_  = ws + OFF_AS;
    float* ad_  = ws + OFF_AD;
    float* cnt  = ws + OFF_CNT;
    float* P    = ws + OFF_P;
    float* part = ws + OFF_PART;
    unsigned int* sb = (unsigned int*)(ws + OFF_S);
    int* ibase  = (int*)(ws + OFF_INT);
    int* rhist  = ibase + IOFF_RHIST;
    int* rstart = ibase + IOFF_RSTART;
    int* rcur   = ibase + IOFF_RCUR;
    int* bcur   = ibase + IOFF_BCUR;
    int* start  = ibase + IOFF_START;
    int* deg    = ibase + IOFF_DEG;
    int* nid    = ibase + IOFF_NID;
    unsigned int* binned = (unsigned int*)(ibase + IOFF_BINNED);
    int* srcs   = ibase + IOFF_SRC;

    k_zero<<<1, 512, 0, stream>>>(rhist);   // rhist(80) + bcur(314) contiguous
    k_a<<<2 * NBLK, 256, 0, stream>>>(x1, x2, rv1, rv2, Wg, asrc, adst, as_, ad_, rhist);
    k_bin<<<2 * BPG, 1024, 0, stream>>>(ei1, ei2, bcur, binned);
    k_ralloc<<<1, 64, 0, stream>>>(rhist, rstart, rcur, cnt);
    k_fine<<<2 * NB, 256, 0, stream>>>(bcur, binned, start, deg, srcs);
    k_nscatter<<<2 * NBLK, 256, 0, stream>>>(rv1, rv2, rcur, nid);
    k_gather<<<2 * NN / 4, 256, 0, stream>>>(start, deg, srcs, as_, ad_, x1, x2, sb);
    k_rnode<<<2 * NR * NCH, 256, 0, stream>>>(rstart, rhist, nid, sb, part);
    k_head<<<2 * NR, 256, 0, stream>>>(part, cnt, Wg, bias, Wh, P);
    k_final<<<1, 1024, 0, stream>>>(P, bh, out);
}

// Round 8
// 140.761 us; speedup vs baseline: 46.3170x; 1.0969x over previous
//
#include <hip/hip_runtime.h>

#define NN 40000      // nodes
#define NE 400000     // edges (before self loops)
#define NF 16         // in features
#define NH 8          // heads
#define NR 40         // routes
#define NK 39         // min(R1,R2)-1 logits kept
#define NEG 0.2f      // leaky relu slope
#define NBLK 157      // (NN+255)/256
#define NCH 16        // chunks per route
#define NB 157        // coarse buckets per graph (dst>>8)
#define SLOT 3328     // entries per bucket slot (mean 2560, +15 sigma)
#define BPG 391       // (NE+1023)/1024 blocks per graph
#define GAB 40        // (NN+1023)/1024 blocks per graph for k_a path

// float region offsets
#define OFF_AS   0                        // [2][NN*NH]
#define OFF_AD   (OFF_AS + 2*NN*NH)       // [2][NN*NH]
#define OFF_P    (OFF_AD + 2*NN*NH)       // [2][NR*NK]
#define OFF_PART (OFF_P + 2*NR*NK)        // [2][NR][NCH][128]
#define OFF_S    (OFF_PART + 2*NR*NCH*128)// [2][NN*64] uints (2 bf16 each)
#define OFF_INT  (OFF_S + 2*NN*64)
// int region (relative to OFF_INT) -- first three zeroed together (474 ints)
#define IOFF_RHIST  0                       // 2*NR
#define IOFF_BCUR   (2*NR)                  // 2*NB
#define IOFF_RCUR   (2*NR + 2*NB)           // 2*NR
#define IOFF_START  (IOFF_RCUR + 2*NR)      // 2*NN (absolute into srcs)
#define IOFF_DEG    (IOFF_START + 2*NN)     // 2*NN
#define IOFF_NID    (IOFF_DEG + 2*NN)       // 2*NN
#define IOFF_BINNED (IOFF_NID + 2*NN)       // 2*NB*SLOT
#define IOFF_SRC    (IOFF_BINNED + 2*NB*SLOT) // 2*NB*SLOT

static __device__ __forceinline__ unsigned int f2bf(float v) {
    unsigned int x = __float_as_uint(v);
    return (x + 0x7FFFu + ((x >> 16) & 1u)) >> 16;   // round-nearest-even
}
static __device__ __forceinline__ float bf2f(unsigned int u) {
    return __uint_as_float(u << 16);
}

// zero the atomic-counter arrays (rhist + bcur + rcur: 474 ints)
__global__ __launch_bounds__(512) void k_zero(int* __restrict__ p) {
    int i = threadIdx.x;
    if (i < 2 * NR + 2 * NB + 2 * NR) p[i] = 0;
}

// fused front: blocks [0,2*GAB) = per-node a_s/a_d + route hist;
//              blocks [2*GAB, ...) = edge coarse-binning
__global__ __launch_bounds__(1024) void k_front(const float* __restrict__ x1,
                                                const float* __restrict__ x2,
                                                const int* __restrict__ rv1,
                                                const int* __restrict__ rv2,
                                                const int* __restrict__ ei1,
                                                const int* __restrict__ ei2,
                                                const float* __restrict__ W,
                                                const float* __restrict__ asrc,
                                                const float* __restrict__ adst,
                                                float* __restrict__ as_,
                                                float* __restrict__ ad_,
                                                int* __restrict__ rhist,
                                                int* __restrict__ bcur,
                                                unsigned int* __restrict__ binned) {
    __shared__ float us[256];
    __shared__ int lh[NR];
    __shared__ int lhb[NB], lbb[NB];
    int tid = threadIdx.x;
    if (blockIdx.x < 2 * GAB) {
        // ---- k_a path: 1024 nodes per block ----
        if (tid < NR) lh[tid] = 0;
        if (tid < 256) {
            int tt = tid & 127;
            int f = tt >> 3, h = tt & 7;
            const float* av = (tid < 128 ? asrc : adst) + h * 64;
            const float* wrow = W + f * 512 + h * 64;
            float su = 0.f;
            for (int c = 0; c < 64; ++c) su += wrow[c] * av[c];
            us[tid] = su;  // [0:128)=u_src(f,h), [128:256)=u_dst(f,h)
        }
        __syncthreads();
        int g = blockIdx.x / GAB;
        int n = (blockIdx.x - g * GAB) * 1024 + tid;
        if (n < NN) {
            const float* x = g ? x2 : x1;
            const int* rv = g ? rv2 : rv1;
            const float4* xp = (const float4*)(x + n * NF);
            float4 v0 = xp[0], v1 = xp[1], v2 = xp[2], v3 = xp[3];
            float xv[16] = {v0.x, v0.y, v0.z, v0.w, v1.x, v1.y, v1.z, v1.w,
                            v2.x, v2.y, v2.z, v2.w, v3.x, v3.y, v3.z, v3.w};
            int o = g * NN * NH + n * NH;
            for (int h = 0; h < NH; ++h) {
                float s1 = 0.f, s2 = 0.f;
                for (int f = 0; f < NF; ++f) {
                    s1 += xv[f] * us[f * 8 + h];
                    s2 += xv[f] * us[128 + f * 8 + h];
                }
                as_[o + h] = s1;
                ad_[o + h] = s2;
            }
            atomicAdd(&lh[rv[n]], 1);
        }
        __syncthreads();
        if (tid < NR && lh[tid]) atomicAdd(&rhist[g * NR + tid], lh[tid]);
    } else {
        // ---- k_bin path ----
        int bid = blockIdx.x - 2 * GAB;
        int g = bid >= BPG;
        int blk = bid - g * BPG;
        if (tid < NB) lhb[tid] = 0;
        __syncthreads();
        int e = blk * 1024 + tid;
        const int* ei = g ? ei2 : ei1;
        unsigned int v = 0;
        int bin = 0, lpos = 0;
        bool valid = (e < NE);
        if (valid) {
            unsigned int s = (unsigned int)ei[e];
            unsigned int dv = (unsigned int)ei[NE + e];
            v = (dv << 16) | s;
            bin = dv >> 8;
            lpos = atomicAdd(&lhb[bin], 1);
        }
        __syncthreads();
        if (tid < NB && lhb[tid]) lbb[tid] = atomicAdd(&bcur[g * NB + tid], lhb[tid]);
        __syncthreads();
        if (valid) {
            int p = lbb[bin] + lpos;
            if (p < SLOT) binned[(g * NB + bin) * SLOT + p] = v;
        }
    }
}

// fused mid: blocks [0,2*NB) = per-bucket fine sort -> srcs/start/deg;
//            blocks [2*NB, ...) = route counting-sort of node ids
__global__ __launch_bounds__(256) void k_mid(const int* __restrict__ bcur,
                                             const unsigned int* __restrict__ binned,
                                             const int* __restrict__ rv1,
                                             const int* __restrict__ rv2,
                                             const int* __restrict__ rhist,
                                             int* __restrict__ rcur,
                                             int* __restrict__ start,
                                             int* __restrict__ deg,
                                             int* __restrict__ srcs,
                                             int* __restrict__ nid) {
    __shared__ unsigned int ed[SLOT];
    __shared__ int hist[256], scn[256];
    __shared__ int lh[NR], lbase[NR], rbase[NR];
    int tid = threadIdx.x;
    if (blockIdx.x < 2 * NB) {
        // ---- fine-sort path ----
        int gb = blockIdx.x;
        int g = gb >= NB;
        int b = gb - g * NB;
        int m = bcur[gb]; if (m > SLOT) m = SLOT;
        int base = gb * SLOT;
        for (int i = tid; i < m; i += 256) ed[i] = binned[base + i];
        hist[tid] = 0;
        __syncthreads();
        for (int i = tid; i < m; i += 256) atomicAdd(&hist[(ed[i] >> 16) & 255], 1);
        __syncthreads();
        int v = hist[tid];
        scn[tid] = v;
        __syncthreads();
        for (int off = 1; off < 256; off <<= 1) {
            int u = (tid >= off) ? scn[tid - off] : 0;
            __syncthreads();
            scn[tid] += u;
            __syncthreads();
        }
        int excl = scn[tid] - v;
        int d = b * 256 + tid;
        if (d < NN) { start[g * NN + d] = base + excl; deg[g * NN + d] = v; }
        hist[tid] = excl;              // reuse as cursor
        __syncthreads();
        for (int i = tid; i < m; i += 256) {
            unsigned int e = ed[i];
            int ld = (e >> 16) & 255;
            int pos = atomicAdd(&hist[ld], 1);
            srcs[base + pos] = (int)(e & 0xffffu);
        }
    } else {
        // ---- node route-sort path ----
        int bid = blockIdx.x - 2 * NB;
        int g = bid / NBLK;
        int n = (bid - g * NBLK) * 256 + tid;
        const int* rv = g ? rv2 : rv1;
        if (tid < NR) lh[tid] = 0;
        __syncthreads();
        int r = 0, lpos = 0;
        bool valid = (n < NN);
        if (valid) { r = rv[n]; lpos = atomicAdd(&lh[r], 1); }
        if (tid == 0) {
            int run = 0;
            for (int rr = 0; rr < NR; ++rr) { rbase[rr] = run; run += rhist[g * NR + rr]; }
        }
        __syncthreads();
        if (tid < NR && lh[tid])
            lbase[tid] = rbase[tid] + atomicAdd(&rcur[g * NR + tid], lh[tid]);
        __syncthreads();
        if (valid) nid[g * NN + lbase[r] + lpos] = n;
    }
}

// gather: per dst a 64-lane wave, lane = (h, q). 8-edge masked batches:
// phase 1: lane computes w for edge-slot q of head h (1 exp per edge-head);
// phase 2: lane accumulates output features (2q, 2q+1) of head h, weights
// broadcast within the h-group via shfl. Output packed bf16 pair.
__global__ __launch_bounds__(256) void k_gather(const int* __restrict__ start,
                                                const int* __restrict__ deg,
                                                const int* __restrict__ srcs,
                                                const float* __restrict__ as_,
                                                const float* __restrict__ ad_,
                                                const float* __restrict__ x1,
                                                const float* __restrict__ x2,
                                                unsigned int* __restrict__ sb) {
    int idx = blockIdx.x * 4 + (threadIdx.x >> 6);   // 0..2*NN-1
    int g = idx >= NN;
    int d = idx - g * NN;
    const float* x = g ? x2 : x1;
    const float* asg = as_ + (size_t)g * NN * NH;
    int lane = threadIdx.x & 63;
    int h = lane >> 3, q = lane & 7;
    float adv = ad_[(size_t)g * NN * NH + d * NH + h];
    // self loop
    float e0 = asg[d * NH + h] + adv;
    e0 = (e0 > 0.f) ? e0 : NEG * e0;
    float w0 = __expf(e0);
    float2 xv = *(const float2*)(x + d * NF + q * 2);
    float wsum = w0;
    float ax = w0 * xv.x, ay = w0 * xv.y;
    int base = __builtin_amdgcn_readfirstlane(start[idx]);
    int dg   = __builtin_amdgcn_readfirstlane(deg[idx]);
    int nbat = (dg + 7) >> 3;
    for (int b = 0; b < nbat; ++b) {
        int off = base + b * 8;
        int lim = dg - b * 8;                 // >0, wave-uniform
        // phase 1: per-lane weight for slot q
        int aq = (q < lim) ? off + q : base;  // clamp (base valid: dg>0 here)
        int sq = srcs[aq];
        float ev = asg[sq * NH + h] + adv;
        ev = (ev > 0.f) ? ev : NEG * ev;
        float wq = (q < lim) ? __expf(ev) : 0.f;
        // phase 2: accumulate 8 edges into (h, 2q..2q+1)
        #pragma unroll
        for (int j = 0; j < 8; ++j) {
            float wj = __shfl(wq, (lane & 56) | j);
            int aj = (j < lim) ? off + j : base;   // uniform select
            int sj = srcs[aj];
            float2 xj = *(const float2*)(x + sj * NF + q * 2);
            wsum += wj;
            ax += wj * xj.x;
            ay += wj * xj.y;
        }
    }
    float inv = 1.0f / wsum;
    unsigned int pk = (f2bf(ay * inv) << 16) | f2bf(ax * inv);
    sb[(size_t)idx * 64 + lane] = pk;
}

// route-sorted register accumulation: block = (g,r,chunk), rstart from rhist
__global__ __launch_bounds__(256) void k_rnode(const int* __restrict__ rhist,
                                               const int* __restrict__ nid,
                                               const unsigned int* __restrict__ sb,
                                               float* __restrict__ part) {
    __shared__ float red[4][128];
    __shared__ int sseg[2];
    int g = blockIdx.x >= NR * NCH;
    int bid = blockIdx.x - g * NR * NCH;
    int r = bid / NCH, ch = bid - r * NCH;
    if (threadIdx.x == 0) {
        int acc = 0;
        for (int rr = 0; rr < r; ++rr) acc += rhist[g * NR + rr];
        sseg[0] = acc;
        sseg[1] = rhist[g * NR + r];
    }
    __syncthreads();
    int seg0 = sseg[0], dgr = sseg[1];
    int csz = (dgr + NCH - 1) / NCH;
    int a = seg0 + ch * csz;
    int b = seg0 + dgr; { int bb = a + csz; if (bb < b) b = bb; }
    int ln = threadIdx.x >> 6, c = threadIdx.x & 63;
    const int* np = nid + g * NN;
    const unsigned int* sg = sb + (size_t)g * NN * 64;
    float sx = 0.f, sy = 0.f;
    for (int i = a + ln; i < b; i += 4) {
        int n = np[i];
        unsigned int pk = sg[(size_t)n * 64 + c];
        sx += bf2f(pk & 0xffffu);
        sy += bf2f(pk >> 16);
    }
    red[ln][c * 2] = sx;
    red[ln][c * 2 + 1] = sy;
    __syncthreads();
    int tid = threadIdx.x;
    if (tid < 128) {
        float s = red[0][tid] + red[1][tid] + red[2][tid] + red[3][tid];
        part[((g * NR + r) * NCH + ch) * 128 + tid] = s;
    }
}

// fused: chunk-partial reduce -> t row -> agg row (512) -> P[g,i,k]
__global__ __launch_bounds__(256) void k_head(const float* __restrict__ part,
                                              const int* __restrict__ rhist,
                                              const float* __restrict__ W,
                                              const float* __restrict__ bias,
                                              const float* __restrict__ Wh,
                                              float* __restrict__ P) {
    __shared__ float trow[128];
    __shared__ float aggL[512];
    __shared__ float scnt;
    int g = blockIdx.x / NR, i = blockIdx.x - g * NR;
    int tid = threadIdx.x;
    if (tid < 128) {
        const float* pp = part + ((g * NR + i) * NCH) * 128 + tid;
        float s = 0.f;
        for (int ch = 0; ch < NCH; ++ch) s += pp[ch * 128];
        trow[tid] = s;
    }
    if (tid == 0) scnt = (float)rhist[g * NR + i];
    __syncthreads();
    for (int hc = tid; hc < 512; hc += 256) {
        int h = hc >> 6;
        float acc = scnt * bias[hc];
        const float* tp = trow + h * 16;
        for (int f = 0; f < 16; ++f) acc += tp[f] * W[f * 512 + hc];
        aggL[hc] = acc;
    }
    __syncthreads();
    if (tid < 4 * NK) {
        int k = tid >> 2, qq = tid & 3;
        const float* wp = Wh + (size_t)(g * 512 + qq * 128) * 61 + k;
        const float* ap = aggL + qq * 128;
        float acc = 0.f;
        for (int d = 0; d < 128; ++d) acc += ap[d] * wp[d * 61];
        acc += __shfl_down(acc, 1);
        acc += __shfl_down(acc, 2);
        if (qq == 0) P[(g * NR + i) * NK + k] = acc;
    }
}

// logits[i,j,k] = P1[i,k]+P2[j,k]+b[k]; global softmax over 62400
__global__ __launch_bounds__(1024) void k_final(const float* __restrict__ P,
                                                const float* __restrict__ bh,
                                                float* __restrict__ out) {
    __shared__ float p1[NR * NK], p2[NR * NK], bsh[NK];
    __shared__ float red[16];
    __shared__ float bc[2];
    int tid = threadIdx.x;
    for (int i = tid; i < NR * NK; i += 1024) { p1[i] = P[i]; p2[i] = P[NR * NK + i]; }
    if (tid < NK) bsh[tid] = bh[tid];
    __syncthreads();
    const int TOT = NR * NR * NK;
    float m = -3.0e38f;
    for (int idx = tid; idx < TOT; idx += 1024) {
        int i = idx / (NR * NK);
        int r = idx - i * (NR * NK);
        int j = r / NK;
        int k = r - j * NK;
        float l = p1[i * NK + k] + p2[j * NK + k] + bsh[k];
        m = fmaxf(m, l);
    }
    for (int off = 32; off > 0; off >>= 1) m = fmaxf(m, __shfl_down(m, off));
    if ((tid & 63) == 0) red[tid >> 6] = m;
    __syncthreads();
    if (tid == 0) {
        float g = red[0];
        for (int w = 1; w < 16; ++w) g = fmaxf(g, red[w]);
        bc[0] = g;
    }
    __syncthreads();
    float gm = bc[0];
    __syncthreads();
    float sum = 0.f;
    for (int idx = tid; idx < TOT; idx += 1024) {
        int i = idx / (NR * NK);
        int r = idx - i * (NR * NK);
        int j = r / NK;
        int k = r - j * NK;
        float l = p1[i * NK + k] + p2[j * NK + k] + bsh[k];
        sum += __expf(l - gm);
    }
    for (int off = 32; off > 0; off >>= 1) sum += __shfl_down(sum, off);
    if ((tid & 63) == 0) red[tid >> 6] = sum;
    __syncthreads();
    if (tid == 0) {
        float g = 0.f;
        for (int w = 0; w < 16; ++w) g += red[w];
        bc[1] = 1.0f / g;
    }
    __syncthreads();
    float inv = bc[1];
    for (int idx = tid; idx < TOT; idx += 1024) {
        int i = idx / (NR * NK);
        int r = idx - i * (NR * NK);
        int j = r / NK;
        int k = r - j * NK;
        float l = p1[i * NK + k] + p2[j * NK + k] + bsh[k];
        out[idx] = __expf(l - gm) * inv;
    }
}

extern "C" void kernel_launch(void* const* d_in, const int* in_sizes, int n_in,
                              void* d_out, int out_size, void* d_ws, size_t ws_size,
                              hipStream_t stream) {
    const float* x1   = (const float*)d_in[0];
    const int*   ei1  = (const int*)d_in[1];
    const int*   rv1  = (const int*)d_in[3];
    const float* x2   = (const float*)d_in[5];
    const int*   ei2  = (const int*)d_in[6];
    const int*   rv2  = (const int*)d_in[8];
    const float* Wg   = (const float*)d_in[10];
    const float* asrc = (const float*)d_in[11];
    const float* adst = (const float*)d_in[12];
    const float* bias = (const float*)d_in[13];
    const float* Wh   = (const float*)d_in[14];
    const float* bh   = (const float*)d_in[15];
    float* out = (float*)d_out;
    float* ws  = (float*)d_ws;

    float* as_  = ws + OFF_AS;
    float* ad_  = ws + OFF_AD;
    float* P    = ws + OFF_P;
    float* part = ws + OFF_PART;
    unsigned int* sb = (unsigned int*)(ws + OFF_S);
    int* ibase  = (int*)(ws + OFF_INT);
    int* rhist  = ibase + IOFF_RHIST;
    int* bcur   = ibase + IOFF_BCUR;
    int* rcur   = ibase + IOFF_RCUR;
    int* start  = ibase + IOFF_START;
    int* deg    = ibase + IOFF_DEG;
    int* nid    = ibase + IOFF_NID;
    unsigned int* binned = (unsigned int*)(ibase + IOFF_BINNED);
    int* srcs   = ibase + IOFF_SRC;

    k_zero<<<1, 512, 0, stream>>>(rhist);
    k_front<<<2 * GAB + 2 * BPG, 1024, 0, stream>>>(x1, x2, rv1, rv2, ei1, ei2,
                                                    Wg, asrc, adst, as_, ad_,
                                                    rhist, bcur, binned);
    k_mid<<<2 * NB + 2 * NBLK, 256, 0, stream>>>(bcur, binned, rv1, rv2, rhist,
                                                 rcur, start, deg, srcs, nid);
    k_gather<<<2 * NN / 4, 256, 0, stream>>>(start, deg, srcs, as_, ad_, x1, x2, sb);
    k_rnode<<<2 * NR * NCH, 256, 0, stream>>>(rhist, nid, sb, part);
    k_head<<<2 * NR, 256, 0, stream>>>(part, rhist, Wg, bias, Wh, P);
    k_final<<<1, 1024, 0, stream>>>(P, bh, out);
}

// Round 9
// 135.107 us; speedup vs baseline: 48.2551x; 1.0418x over previous
//
#include <hip/hip_runtime.h>

#define NN 40000      // nodes
#define NE 400000     // edges (before self loops)
#define NF 16         // in features
#define NH 8          // heads
#define NR 40         // routes
#define NK 39         // min(R1,R2)-1 logits kept
#define NEG 0.2f      // leaky relu slope
#define NBLK 157      // (NN+255)/256
#define NCH 16        // chunks per route
#define NB 157        // coarse buckets per graph (dst>>8)
#define SLOT 3328     // entries per bucket slot (mean 2560, +15 sigma)
#define BPG 391       // (NE+1023)/1024 blocks per graph
#define GAB 40        // (NN+1023)/1024 blocks per graph for k_a path

// float region offsets
#define OFF_AS   0                        // [2][NN*NH]
#define OFF_AD   (OFF_AS + 2*NN*NH)       // [2][NN*NH]
#define OFF_P    (OFF_AD + 2*NN*NH)       // [2][NR*NK]
#define OFF_PART (OFF_P + 2*NR*NK)        // [2][NR][NCH][128]
#define OFF_S    (OFF_PART + 2*NR*NCH*128)// [2][NN*64] uints (2 bf16 each)
#define OFF_INT  (OFF_S + 2*NN*64)
// int region (relative to OFF_INT) -- first three zeroed together (474 ints)
#define IOFF_RHIST  0                       // 2*NR
#define IOFF_BCUR   (2*NR)                  // 2*NB
#define IOFF_RCUR   (2*NR + 2*NB)           // 2*NR
#define IOFF_START  (IOFF_RCUR + 2*NR)      // 2*NN (absolute into srcs)
#define IOFF_DEG    (IOFF_START + 2*NN)     // 2*NN
#define IOFF_NID    (IOFF_DEG + 2*NN)       // 2*NN
#define IOFF_BINNED (IOFF_NID + 2*NN)       // 2*NB*SLOT
#define IOFF_SRC    (IOFF_BINNED + 2*NB*SLOT) // 2*NB*SLOT

static __device__ __forceinline__ unsigned int f2bf(float v) {
    unsigned int x = __float_as_uint(v);
    return (x + 0x7FFFu + ((x >> 16) & 1u)) >> 16;   // round-nearest-even
}
static __device__ __forceinline__ float bf2f(unsigned int u) {
    return __uint_as_float(u << 16);
}

// zero the atomic-counter arrays (rhist + bcur + rcur: 474 ints)
__global__ __launch_bounds__(512) void k_zero(int* __restrict__ p) {
    int i = threadIdx.x;
    if (i < 2 * NR + 2 * NB + 2 * NR) p[i] = 0;
}

// fused front: blocks [0,2*GAB) = per-node a_s/a_d + route hist;
//              blocks [2*GAB, ...) = edge coarse-binning
__global__ __launch_bounds__(1024) void k_front(const float* __restrict__ x1,
                                                const float* __restrict__ x2,
                                                const int* __restrict__ rv1,
                                                const int* __restrict__ rv2,
                                                const int* __restrict__ ei1,
                                                const int* __restrict__ ei2,
                                                const float* __restrict__ W,
                                                const float* __restrict__ asrc,
                                                const float* __restrict__ adst,
                                                float* __restrict__ as_,
                                                float* __restrict__ ad_,
                                                int* __restrict__ rhist,
                                                int* __restrict__ bcur,
                                                unsigned int* __restrict__ binned) {
    __shared__ float us[256];
    __shared__ int lh[NR];
    __shared__ int lhb[NB], lbb[NB];
    int tid = threadIdx.x;
    if (blockIdx.x < 2 * GAB) {
        // ---- k_a path: 1024 nodes per block ----
        if (tid < NR) lh[tid] = 0;
        if (tid < 256) {
            int tt = tid & 127;
            int f = tt >> 3, h = tt & 7;
            const float* av = (tid < 128 ? asrc : adst) + h * 64;
            const float* wrow = W + f * 512 + h * 64;
            float su = 0.f;
            for (int c = 0; c < 64; ++c) su += wrow[c] * av[c];
            us[tid] = su;  // [0:128)=u_src(f,h), [128:256)=u_dst(f,h)
        }
        __syncthreads();
        int g = blockIdx.x / GAB;
        int n = (blockIdx.x - g * GAB) * 1024 + tid;
        if (n < NN) {
            const float* x = g ? x2 : x1;
            const int* rv = g ? rv2 : rv1;
            const float4* xp = (const float4*)(x + n * NF);
            float4 v0 = xp[0], v1 = xp[1], v2 = xp[2], v3 = xp[3];
            float xv[16] = {v0.x, v0.y, v0.z, v0.w, v1.x, v1.y, v1.z, v1.w,
                            v2.x, v2.y, v2.z, v2.w, v3.x, v3.y, v3.z, v3.w};
            int o = g * NN * NH + n * NH;
            for (int h = 0; h < NH; ++h) {
                float s1 = 0.f, s2 = 0.f;
                for (int f = 0; f < NF; ++f) {
                    s1 += xv[f] * us[f * 8 + h];
                    s2 += xv[f] * us[128 + f * 8 + h];
                }
                as_[o + h] = s1;
                ad_[o + h] = s2;
            }
            atomicAdd(&lh[rv[n]], 1);
        }
        __syncthreads();
        if (tid < NR && lh[tid]) atomicAdd(&rhist[g * NR + tid], lh[tid]);
    } else {
        // ---- k_bin path ----
        int bid = blockIdx.x - 2 * GAB;
        int g = bid >= BPG;
        int blk = bid - g * BPG;
        if (tid < NB) lhb[tid] = 0;
        __syncthreads();
        int e = blk * 1024 + tid;
        const int* ei = g ? ei2 : ei1;
        unsigned int v = 0;
        int bin = 0, lpos = 0;
        bool valid = (e < NE);
        if (valid) {
            unsigned int s = (unsigned int)ei[e];
            unsigned int dv = (unsigned int)ei[NE + e];
            v = (dv << 16) | s;
            bin = dv >> 8;
            lpos = atomicAdd(&lhb[bin], 1);
        }
        __syncthreads();
        if (tid < NB && lhb[tid]) lbb[tid] = atomicAdd(&bcur[g * NB + tid], lhb[tid]);
        __syncthreads();
        if (valid) {
            int p = lbb[bin] + lpos;
            if (p < SLOT) binned[(g * NB + bin) * SLOT + p] = v;
        }
    }
}

// fused mid: blocks [0,2*NB) = per-bucket fine sort -> srcs/start/deg;
//            blocks [2*NB, ...) = route counting-sort of node ids
__global__ __launch_bounds__(256) void k_mid(const int* __restrict__ bcur,
                                             const unsigned int* __restrict__ binned,
                                             const int* __restrict__ rv1,
                                             const int* __restrict__ rv2,
                                             const int* __restrict__ rhist,
                                             int* __restrict__ rcur,
                                             int* __restrict__ start,
                                             int* __restrict__ deg,
                                             int* __restrict__ srcs,
                                             int* __restrict__ nid) {
    __shared__ unsigned int ed[SLOT];
    __shared__ int hist[256], scn[256];
    __shared__ int lh[NR], lbase[NR], rbase[NR];
    int tid = threadIdx.x;
    if (blockIdx.x < 2 * NB) {
        // ---- fine-sort path ----
        int gb = blockIdx.x;
        int g = gb >= NB;
        int b = gb - g * NB;
        int m = bcur[gb]; if (m > SLOT) m = SLOT;
        int base = gb * SLOT;
        for (int i = tid; i < m; i += 256) ed[i] = binned[base + i];
        hist[tid] = 0;
        __syncthreads();
        for (int i = tid; i < m; i += 256) atomicAdd(&hist[(ed[i] >> 16) & 255], 1);
        __syncthreads();
        int v = hist[tid];
        scn[tid] = v;
        __syncthreads();
        for (int off = 1; off < 256; off <<= 1) {
            int u = (tid >= off) ? scn[tid - off] : 0;
            __syncthreads();
            scn[tid] += u;
            __syncthreads();
        }
        int excl = scn[tid] - v;
        int d = b * 256 + tid;
        if (d < NN) { start[g * NN + d] = base + excl; deg[g * NN + d] = v; }
        hist[tid] = excl;              // reuse as cursor
        __syncthreads();
        for (int i = tid; i < m; i += 256) {
            unsigned int e = ed[i];
            int ld = (e >> 16) & 255;
            int pos = atomicAdd(&hist[ld], 1);
            srcs[base + pos] = (int)(e & 0xffffu);
        }
    } else {
        // ---- node route-sort path ----
        int bid = blockIdx.x - 2 * NB;
        int g = bid / NBLK;
        int n = (bid - g * NBLK) * 256 + tid;
        const int* rv = g ? rv2 : rv1;
        if (tid < NR) lh[tid] = 0;
        __syncthreads();
        int r = 0, lpos = 0;
        bool valid = (n < NN);
        if (valid) { r = rv[n]; lpos = atomicAdd(&lh[r], 1); }
        if (tid == 0) {
            int run = 0;
            for (int rr = 0; rr < NR; ++rr) { rbase[rr] = run; run += rhist[g * NR + rr]; }
        }
        __syncthreads();
        if (tid < NR && lh[tid])
            lbase[tid] = rbase[tid] + atomicAdd(&rcur[g * NR + tid], lh[tid]);
        __syncthreads();
        if (valid) nid[g * NN + lbase[r] + lpos] = n;
    }
}

// gather: per dst a 64-lane wave. 8-edge masked batches, shfl redistribution:
// phase 1 (lane = h*8 + slot q): 1 srcs load + 1 as_ load + 1 exp -> w[h][q]
// phase 1b (lane = (j=lane>>3, q)): s_j via shfl, ONE float2 x load -> xr[j][q]
// phase 2 (lane = (h,q)): w_j, x_j via shfl -> FMA. VMEM 3/batch (was 18).
__global__ __launch_bounds__(256) void k_gather(const int* __restrict__ start,
                                                const int* __restrict__ deg,
                                                const int* __restrict__ srcs,
                                                const float* __restrict__ as_,
                                                const float* __restrict__ ad_,
                                                const float* __restrict__ x1,
                                                const float* __restrict__ x2,
                                                unsigned int* __restrict__ sb) {
    int idx = blockIdx.x * 4 + (threadIdx.x >> 6);   // 0..2*NN-1
    int g = idx >= NN;
    int d = idx - g * NN;
    const float* x = g ? x2 : x1;
    const float* asg = as_ + (size_t)g * NN * NH;
    int lane = threadIdx.x & 63;
    int h = lane >> 3, q = lane & 7;
    float adv = ad_[(size_t)g * NN * NH + d * NH + h];
    // self loop
    float e0 = asg[d * NH + h] + adv;
    e0 = (e0 > 0.f) ? e0 : NEG * e0;
    float w0 = __expf(e0);
    float2 xv = *(const float2*)(x + d * NF + q * 2);
    float wsum = w0;
    float ax = w0 * xv.x, ay = w0 * xv.y;
    int base = __builtin_amdgcn_readfirstlane(start[idx]);
    int dg   = __builtin_amdgcn_readfirstlane(deg[idx]);
    int nbat = (dg + 7) >> 3;
    for (int b = 0; b < nbat; ++b) {
        int off = base + b * 8;
        int lim = dg - b * 8;                 // >0, wave-uniform
        // phase 1: weight for slot q of head h
        int aq = (q < lim) ? off + q : base;  // clamp (base valid: dg>0 here)
        int sq = srcs[aq];
        float ev = asg[sq * NH + h] + adv;
        ev = (ev > 0.f) ? ev : NEG * ev;
        float wq = (q < lim) ? __expf(ev) : 0.f;
        // phase 1b: lane as (j = lane>>3, q) loads ONE float2 of row s_j
        int sB = __shfl(sq, lane >> 3);       // s_j lives in lane (h=0, q=j)
        float2 xr = *(const float2*)(x + sB * NF + q * 2);
        // phase 2: lane (h,q) accumulates over j via shfl
        #pragma unroll
        for (int j = 0; j < 8; ++j) {
            float wj  = __shfl(wq,   (lane & 56) | j);   // w[h][j]
            float xjx = __shfl(xr.x, (j << 3) | q);      // x[s_j][2q]
            float xjy = __shfl(xr.y, (j << 3) | q);      // x[s_j][2q+1]
            wsum += wj;
            ax += wj * xjx;
            ay += wj * xjy;
        }
    }
    float inv = 1.0f / wsum;
    unsigned int pk = (f2bf(ay * inv) << 16) | f2bf(ax * inv);
    sb[(size_t)idx * 64 + lane] = pk;
}

// route-sorted register accumulation: block = (g,r,chunk), rstart from rhist
__global__ __launch_bounds__(256) void k_rnode(const int* __restrict__ rhist,
                                               const int* __restrict__ nid,
                                               const unsigned int* __restrict__ sb,
                                               float* __restrict__ part) {
    __shared__ float red[4][128];
    __shared__ int sseg[2];
    int g = blockIdx.x >= NR * NCH;
    int bid = blockIdx.x - g * NR * NCH;
    int r = bid / NCH, ch = bid - r * NCH;
    if (threadIdx.x == 0) {
        int acc = 0;
        for (int rr = 0; rr < r; ++rr) acc += rhist[g * NR + rr];
        sseg[0] = acc;
        sseg[1] = rhist[g * NR + r];
    }
    __syncthreads();
    int seg0 = sseg[0], dgr = sseg[1];
    int csz = (dgr + NCH - 1) / NCH;
    int a = seg0 + ch * csz;
    int b = seg0 + dgr; { int bb = a + csz; if (bb < b) b = bb; }
    int ln = threadIdx.x >> 6, c = threadIdx.x & 63;
    const int* np = nid + g * NN;
    const unsigned int* sg = sb + (size_t)g * NN * 64;
    float sx = 0.f, sy = 0.f;
    for (int i = a + ln; i < b; i += 4) {
        int n = np[i];
        unsigned int pk = sg[(size_t)n * 64 + c];
        sx += bf2f(pk & 0xffffu);
        sy += bf2f(pk >> 16);
    }
    red[ln][c * 2] = sx;
    red[ln][c * 2 + 1] = sy;
    __syncthreads();
    int tid = threadIdx.x;
    if (tid < 128) {
        float s = red[0][tid] + red[1][tid] + red[2][tid] + red[3][tid];
        part[((g * NR + r) * NCH + ch) * 128 + tid] = s;
    }
}

// fused: chunk-partial reduce -> t row -> agg row (512) -> P[g,i,k]
__global__ __launch_bounds__(256) void k_head(const float* __restrict__ part,
                                              const int* __restrict__ rhist,
                                              const float* __restrict__ W,
                                              const float* __restrict__ bias,
                                              const float* __restrict__ Wh,
                                              float* __restrict__ P) {
    __shared__ float trow[128];
    __shared__ float aggL[512];
    __shared__ float scnt;
    int g = blockIdx.x / NR, i = blockIdx.x - g * NR;
    int tid = threadIdx.x;
    if (tid < 128) {
        const float* pp = part + ((g * NR + i) * NCH) * 128 + tid;
        float s = 0.f;
        for (int ch = 0; ch < NCH; ++ch) s += pp[ch * 128];
        trow[tid] = s;
    }
    if (tid == 0) scnt = (float)rhist[g * NR + i];
    __syncthreads();
    for (int hc = tid; hc < 512; hc += 256) {
        int h = hc >> 6;
        float acc = scnt * bias[hc];
        const float* tp = trow + h * 16;
        for (int f = 0; f < 16; ++f) acc += tp[f] * W[f * 512 + hc];
        aggL[hc] = acc;
    }
    __syncthreads();
    if (tid < 4 * NK) {
        int k = tid >> 2, qq = tid & 3;
        const float* wp = Wh + (size_t)(g * 512 + qq * 128) * 61 + k;
        const float* ap = aggL + qq * 128;
        float acc = 0.f;
        for (int d = 0; d < 128; ++d) acc += ap[d] * wp[d * 61];
        acc += __shfl_down(acc, 1);
        acc += __shfl_down(acc, 2);
        if (qq == 0) P[(g * NR + i) * NK + k] = acc;
    }
}

// logits[i,j,k] = P1[i,k]+P2[j,k]+b[k]; global softmax over 62400
__global__ __launch_bounds__(1024) void k_final(const float* __restrict__ P,
                                                const float* __restrict__ bh,
                                                float* __restrict__ out) {
    __shared__ float p1[NR * NK], p2[NR * NK], bsh[NK];
    __shared__ float red[16];
    __shared__ float bc[2];
    int tid = threadIdx.x;
    for (int i = tid; i < NR * NK; i += 1024) { p1[i] = P[i]; p2[i] = P[NR * NK + i]; }
    if (tid < NK) bsh[tid] = bh[tid];
    __syncthreads();
    const int TOT = NR * NR * NK;
    float m = -3.0e38f;
    for (int idx = tid; idx < TOT; idx += 1024) {
        int i = idx / (NR * NK);
        int r = idx - i * (NR * NK);
        int j = r / NK;
        int k = r - j * NK;
        float l = p1[i * NK + k] + p2[j * NK + k] + bsh[k];
        m = fmaxf(m, l);
    }
    for (int off = 32; off > 0; off >>= 1) m = fmaxf(m, __shfl_down(m, off));
    if ((tid & 63) == 0) red[tid >> 6] = m;
    __syncthreads();
    if (tid == 0) {
        float g = red[0];
        for (int w = 1; w < 16; ++w) g = fmaxf(g, red[w]);
        bc[0] = g;
    }
    __syncthreads();
    float gm = bc[0];
    __syncthreads();
    float sum = 0.f;
    for (int idx = tid; idx < TOT; idx += 1024) {
        int i = idx / (NR * NK);
        int r = idx - i * (NR * NK);
        int j = r / NK;
        int k = r - j * NK;
        float l = p1[i * NK + k] + p2[j * NK + k] + bsh[k];
        sum += __expf(l - gm);
    }
    for (int off = 32; off > 0; off >>= 1) sum += __shfl_down(sum, off);
    if ((tid & 63) == 0) red[tid >> 6] = sum;
    __syncthreads();
    if (tid == 0) {
        float g = 0.f;
        for (int w = 0; w < 16; ++w) g += red[w];
        bc[1] = 1.0f / g;
    }
    __syncthreads();
    float inv = bc[1];
    for (int idx = tid; idx < TOT; idx += 1024) {
        int i = idx / (NR * NK);
        int r = idx - i * (NR * NK);
        int j = r / NK;
        int k = r - j * NK;
        float l = p1[i * NK + k] + p2[j * NK + k] + bsh[k];
        out[idx] = __expf(l - gm) * inv;
    }
}

extern "C" void kernel_launch(void* const* d_in, const int* in_sizes, int n_in,
                              void* d_out, int out_size, void* d_ws, size_t ws_size,
                              hipStream_t stream) {
    const float* x1   = (const float*)d_in[0];
    const int*   ei1  = (const int*)d_in[1];
    const int*   rv1  = (const int*)d_in[3];
    const float* x2   = (const float*)d_in[5];
    const int*   ei2  = (const int*)d_in[6];
    const int*   rv2  = (const int*)d_in[8];
    const float* Wg   = (const float*)d_in[10];
    const float* asrc = (const float*)d_in[11];
    const float* adst = (const float*)d_in[12];
    const float* bias = (const float*)d_in[13];
    const float* Wh   = (const float*)d_in[14];
    const float* bh   = (const float*)d_in[15];
    float* out = (float*)d_out;
    float* ws  = (float*)d_ws;

    float* as_  = ws + OFF_AS;
    float* ad_  = ws + OFF_AD;
    float* P    = ws + OFF_P;
    float* part = ws + OFF_PART;
    unsigned int* sb = (unsigned int*)(ws + OFF_S);
    int* ibase  = (int*)(ws + OFF_INT);
    int* rhist  = ibase + IOFF_RHIST;
    int* bcur   = ibase + IOFF_BCUR;
    int* rcur   = ibase + IOFF_RCUR;
    int* start  = ibase + IOFF_START;
    int* deg    = ibase + IOFF_DEG;
    int* nid    = ibase + IOFF_NID;
    unsigned int* binned = (unsigned int*)(ibase + IOFF_BINNED);
    int* srcs   = ibase + IOFF_SRC;

    k_zero<<<1, 512, 0, stream>>>(rhist);
    k_front<<<2 * GAB + 2 * BPG, 1024, 0, stream>>>(x1, x2, rv1, rv2, ei1, ei2,
                                                    Wg, asrc, adst, as_, ad_,
                                                    rhist, bcur, binned);
    k_mid<<<2 * NB + 2 * NBLK, 256, 0, stream>>>(bcur, binned, rv1, rv2, rhist,
                                                 rcur, start, deg, srcs, nid);
    k_gather<<<2 * NN / 4, 256, 0, stream>>>(start, deg, srcs, as_, ad_, x1, x2, sb);
    k_rnode<<<2 * NR * NCH, 256, 0, stream>>>(rhist, nid, sb, part);
    k_head<<<2 * NR, 256, 0, stream>>>(part, rhist, Wg, bias, Wh, P);
    k_final<<<1, 1024, 0, stream>>>(P, bh, out);
}